// Round 1
// baseline (1082.244 us; speedup 1.0000x reference)
//
#include <hip/hip_runtime.h>
#include <math.h>

// ---------------------------------------------------------------------------
// FeatureMatching: conv tower -> top-k keypoints -> softmax corr gather ->
// weighted DLT -> LAPACK-faithful sgesdd(QR path) SVD for H = Vh[:,:,-1].
// All f32. B=2, C=256, H=W=64, HW=4096, K=512.
// ---------------------------------------------------------------------------

#define HW4 4096
#define NIMG 4   // imgs 0,1 = rgb batches; 2,3 = ir batches

// ws layout (floats)
#define OFF_X1   0L
#define OFF_X2   (OFF_X1 + 4L*128*4096)
#define OFF_RESP (OFF_X2 + 4L*128*4096)
#define OFF_INVN (OFF_RESP + 4L*4096)
#define OFF_TOPI (OFF_INVN + 4L*4096)      /* 4*512 ints */
#define OFF_WTS  (OFF_TOPI + 4L*512)
#define OFF_A    (OFF_WTS + 2L*512)

__device__ __forceinline__ float silu_f(float y) { return y / (1.f + expf(-y)); }

// ---------------- conv1: 1x1 256->128 + BN + SiLU ----------------
__global__ __launch_bounds__(256) void fm_conv1(
    const float* __restrict__ rgb, const float* __restrict__ ir,
    const float* __restrict__ w, const float* __restrict__ g,
    const float* __restrict__ bb, const float* __restrict__ mm,
    const float* __restrict__ vv, float* __restrict__ x1) {
  __shared__ float wsm[256];
  int bid = blockIdx.x;
  int pblk = bid & 15, oc = (bid >> 4) & 127, img = bid >> 11;
  int tid = threadIdx.x;
  const float* src = (img < 2) ? (rgb + (long)img*256*HW4) : (ir + (long)(img-2)*256*HW4);
  wsm[tid] = w[oc*256 + tid];
  __syncthreads();
  int p = pblk*256 + tid;
  float acc = 0.f;
  #pragma unroll 8
  for (int ic = 0; ic < 256; ++ic) acc = fmaf(wsm[ic], src[ic*HW4 + p], acc);
  float inv = 1.f / sqrtf(vv[oc] + 1e-5f);
  float y = (acc - mm[oc]) * (g[oc]*inv) + bb[oc];
  x1[((long)img*128 + oc)*HW4 + p] = silu_f(y);
}

// ---------------- conv3: 3x3 128->128 SAME + BN+SiLU + BN_e+ReLU -----------
__global__ __launch_bounds__(256) void fm_conv3(
    const float* __restrict__ x1, const float* __restrict__ w,
    const float* __restrict__ g1, const float* __restrict__ b1,
    const float* __restrict__ m1, const float* __restrict__ v1,
    const float* __restrict__ ge, const float* __restrict__ be,
    const float* __restrict__ me, const float* __restrict__ ve,
    float* __restrict__ x2) {
  __shared__ float t[18*18];
  __shared__ float wv[9];
  int bid = blockIdx.x;
  int tile = bid & 15, oc = (bid >> 4) & 127, img = bid >> 11;
  int ty0 = (tile >> 2) * 16, tx0 = (tile & 3) * 16;
  int tid = threadIdx.x;
  int ly = tid >> 4, lx = tid & 15;
  float acc = 0.f;
  for (int ic = 0; ic < 128; ++ic) {
    for (int i = tid; i < 324; i += 256) {
      int ry = i / 18, rx = i % 18;
      int gy = ty0 + ry - 1, gx = tx0 + rx - 1;
      float val = 0.f;
      if (gy >= 0 && gy < 64 && gx >= 0 && gx < 64)
        val = x1[((long)img*128 + ic)*HW4 + gy*64 + gx];
      t[i] = val;
    }
    if (tid < 9) wv[tid] = w[((long)oc*128 + ic)*9 + tid];
    __syncthreads();
    acc = fmaf(wv[0], t[ly*18 + lx],       acc);
    acc = fmaf(wv[1], t[ly*18 + lx + 1],   acc);
    acc = fmaf(wv[2], t[ly*18 + lx + 2],   acc);
    acc = fmaf(wv[3], t[(ly+1)*18 + lx],   acc);
    acc = fmaf(wv[4], t[(ly+1)*18 + lx+1], acc);
    acc = fmaf(wv[5], t[(ly+1)*18 + lx+2], acc);
    acc = fmaf(wv[6], t[(ly+2)*18 + lx],   acc);
    acc = fmaf(wv[7], t[(ly+2)*18 + lx+1], acc);
    acc = fmaf(wv[8], t[(ly+2)*18 + lx+2], acc);
    __syncthreads();
  }
  float inv1 = 1.f / sqrtf(v1[oc] + 1e-5f);
  float y = (acc - m1[oc]) * (g1[oc]*inv1) + b1[oc];
  y = silu_f(y);
  float inve = 1.f / sqrtf(ve[oc] + 1e-5f);
  float z = (y - me[oc]) * (ge[oc]*inve) + be[oc];
  z = fmaxf(z, 0.f);
  int p = (ty0 + ly)*64 + tx0 + lx;
  x2[((long)img*128 + oc)*HW4 + p] = z;
}

// ---------------- conv2: 1x1 128->64 + BN + SiLU -> desc (into d_out) ------
__global__ __launch_bounds__(256) void fm_conv2(
    const float* __restrict__ x2, const float* __restrict__ w,
    const float* __restrict__ g, const float* __restrict__ bb,
    const float* __restrict__ mm, const float* __restrict__ vv,
    float* __restrict__ out) {
  __shared__ float wsm[128];
  int bid = blockIdx.x;
  int pblk = bid & 15, oc = (bid >> 4) & 63, img = bid >> 10;
  int tid = threadIdx.x;
  if (tid < 128) wsm[tid] = w[oc*128 + tid];
  __syncthreads();
  int p = pblk*256 + tid;
  const float* src = x2 + (long)img*128*HW4;
  float acc = 0.f;
  #pragma unroll 8
  for (int ic = 0; ic < 128; ++ic) acc = fmaf(wsm[ic], src[ic*HW4 + p], acc);
  float inv = 1.f / sqrtf(vv[oc] + 1e-5f);
  float y = (acc - mm[oc]) * (g[oc]*inv) + bb[oc];
  out[18 + (long)img*262144 + oc*HW4 + p] = silu_f(y);
}

// ---------------- resp + inv-norm ----------------
__global__ __launch_bounds__(256) void fm_resp(
    const float* __restrict__ out, float* __restrict__ resp, float* __restrict__ invn) {
  int t = blockIdx.x*256 + threadIdx.x;
  if (t >= NIMG*HW4) return;
  int img = t >> 12, p = t & 4095;
  const float* d = out + 18 + (long)img*262144;
  float s = 0.f;
  #pragma unroll
  for (int c = 0; c < 64; ++c) { float x = d[c*HW4 + p]; s = fmaf(x, x, s); }
  float r = sqrtf(s);
  resp[t] = r;
  invn[t] = 1.f / fmaxf(r, 1e-12f);
}

// ---------------- top-512 via full bitonic sort (desc value, asc index) ----
__global__ __launch_bounds__(1024) void fm_sort(
    const float* __restrict__ resp, int* __restrict__ topidx) {
  __shared__ unsigned long long keys[4096];
  int img = blockIdx.x, tid = threadIdx.x;
  const float* r = resp + (long)img*HW4;
  for (int i = tid; i < 4096; i += 1024) {
    unsigned int vb = __float_as_uint(r[i]);   // resp >= 0 -> bits monotone
    keys[i] = ((unsigned long long)vb << 32) | (unsigned int)(4095 - i);
  }
  __syncthreads();
  for (int k = 2; k <= 4096; k <<= 1) {
    for (int j = k >> 1; j > 0; j >>= 1) {
      for (int t = tid; t < 2048; t += 1024) {
        int i = 2*t - (t & (j - 1));
        int ixj = i ^ j;
        bool up = ((i & k) == 0);
        unsigned long long a = keys[i], b = keys[ixj];
        if ((a < b) == up) { keys[i] = b; keys[ixj] = a; }
      }
      __syncthreads();
    }
  }
  if (tid < 512) topidx[img*512 + tid] = 4095 - (int)(keys[tid] & 0xFFFFFFFFull);
}

// ---------------- softmax-weight gather (one block per keypoint) -----------
__global__ __launch_bounds__(256) void fm_wts(
    const float* __restrict__ out, const float* __restrict__ invn,
    const int* __restrict__ topidx, float* __restrict__ wts) {
  int kq = blockIdx.x, b = blockIdx.y, tid = threadIdx.x;
  const float* d1 = out + 18 + (long)b*262144;
  const float* d2 = out + 18 + (long)(2 + b)*262144;
  const float* in1 = invn + (long)b*HW4;
  const float* in2 = invn + (long)(2 + b)*HW4;
  int row = topidx[b*512 + kq];
  int col = topidx[(2 + b)*512 + kq];
  __shared__ float q[64];
  if (tid < 64) q[tid] = d1[tid*HW4 + row] * in1[row];
  __syncthreads();
  float mloc = -INFINITY, sloc = 0.f;
  for (int j = tid; j < 4096; j += 256) {
    float dot = 0.f;
    #pragma unroll
    for (int c = 0; c < 64; ++c) dot = fmaf(q[c], d2[c*HW4 + j], dot);
    float v = dot * in2[j];
    if (v > mloc) { sloc = sloc*expf(mloc - v) + 1.f; mloc = v; }
    else sloc += expf(v - mloc);
  }
  __shared__ float sm[256], ss[256];
  sm[tid] = mloc; ss[tid] = sloc;
  __syncthreads();
  for (int off = 128; off > 0; off >>= 1) {
    if (tid < off) {
      float m1 = sm[tid], m2 = sm[tid + off];
      float M = fmaxf(m1, m2);
      ss[tid] = ss[tid]*expf(m1 - M) + ss[tid + off]*expf(m2 - M);
      sm[tid] = M;
    }
    __syncthreads();
  }
  if (tid == 0) {
    float dot = 0.f;
    for (int c = 0; c < 64; ++c) dot = fmaf(q[c], d2[c*HW4 + col], dot);
    float v = dot * in2[col];
    wts[b*512 + kq] = expf(v - sm[0]) / ss[0];
  }
}

// ---------------- build DLT rows ----------------
__global__ __launch_bounds__(256) void fm_build(
    const int* __restrict__ topidx, const float* __restrict__ wts,
    float* __restrict__ A) {
  int t = blockIdx.x*256 + threadIdx.x;
  if (t >= 1024) return;
  int b = t >> 9, k = t & 511;
  int i1 = topidx[b*512 + k], i2 = topidx[(2 + b)*512 + k];
  float w = wts[b*512 + k];
  float x1 = (float)(i1 & 63) / 63.f * 2.f - 1.f;
  float y1 = (float)(i1 >> 6) / 63.f * 2.f - 1.f;
  float x2 = (float)(i2 & 63) / 63.f * 2.f - 1.f;
  float y2 = (float)(i2 >> 6) / 63.f * 2.f - 1.f;
  float* r = A + ((long)b*1024 + 2*k)*9;
  r[0] = x1*w;  r[1] = y1*w;  r[2] = w;
  r[3] = 0.f;   r[4] = 0.f;   r[5] = 0.f;
  r[6] = (-x2*x1)*w; r[7] = (-x2*y1)*w; r[8] = (-x2)*w;
  r[9]  = 0.f;  r[10] = 0.f;  r[11] = 0.f;
  r[12] = x1*w; r[13] = y1*w; r[14] = w;
  r[15] = (-y2*x1)*w; r[16] = (-y2*y1)*w; r[17] = (-y2)*w;
}

// =========================== LAPACK ports ===================================
// slartg, LAPACK >= 3.10 convention: c >= 0, r = sign(f)*hypot.
__device__ void lap_slartg(float f, float g, float* cs, float* sn, float* r) {
  if (g == 0.f) { *cs = 1.f; *sn = 0.f; *r = f; }
  else if (f == 0.f) { *cs = 0.f; *sn = copysignf(1.f, g); *r = fabsf(g); }
  else {
    float d = sqrtf(f*f + g*g);
    *cs = fabsf(f) / d;
    *r = copysignf(d, f);
    *sn = g / (*r);
  }
}

__device__ void lap_slas2(float f, float g, float h, float* ssmin, float* ssmax) {
  float fa = fabsf(f), ga = fabsf(g), ha = fabsf(h);
  float fhmn = fminf(fa, ha), fhmx = fmaxf(fa, ha);
  if (fhmn == 0.f) {
    *ssmin = 0.f;
    if (fhmx == 0.f) *ssmax = ga;
    else {
      float mx = fmaxf(fhmx, ga), mn = fminf(fhmx, ga);
      float q = mn / mx;
      *ssmax = mx * sqrtf(1.f + q*q);
    }
  } else {
    if (ga < fhmx) {
      float as_ = 1.f + fhmn/fhmx;
      float at_ = (fhmx - fhmn)/fhmx;
      float au = ga/fhmx; au = au*au;
      float c = 2.f / (sqrtf(as_*as_ + au) + sqrtf(at_*at_ + au));
      *ssmin = fhmn*c;
      *ssmax = fhmx/c;
    } else {
      float au = fhmx/ga;
      if (au == 0.f) { *ssmin = (fhmn*fhmx)/ga; *ssmax = ga; }
      else {
        float as_ = 1.f + fhmn/fhmx;
        float at_ = (fhmx - fhmn)/fhmx;
        float t1 = as_*au, t2 = at_*au;
        float c = 1.f / (sqrtf(1.f + t1*t1) + sqrtf(1.f + t2*t2));
        float smn = (fhmn*c)*au;
        *ssmin = smn + smn;
        *ssmax = ga/(c + c);
      }
    }
  }
}

__device__ void lap_slasv2(float f, float g, float h, float* ssmin, float* ssmax,
                           float* snr, float* csr, float* snl, float* csl) {
  const float epsv = 5.9604645e-08f;
  float ft = f, fa = fabsf(f), ht = h, ha = fabsf(h);
  int pmax = 1;
  bool swap_ = (ha > fa);
  if (swap_) { pmax = 3; float tmp = ft; ft = ht; ht = tmp; tmp = fa; fa = ha; ha = tmp; }
  float gt = g, ga = fabsf(gt);
  float clt = 0.f, crt = 0.f, slt = 0.f, srt = 0.f;
  if (ga == 0.f) { *ssmin = ha; *ssmax = fa; clt = 1.f; crt = 1.f; slt = 0.f; srt = 0.f; }
  else {
    bool gasmal = true;
    if (ga > fa) {
      pmax = 2;
      if ((fa/ga) < epsv) {
        gasmal = false;
        *ssmax = ga;
        if (ha > 1.f) *ssmin = fa/(ga/ha); else *ssmin = (fa/ga)*ha;
        clt = 1.f; slt = ht/gt; srt = 1.f; crt = ft/gt;
      }
    }
    if (gasmal) {
      float d = fa - ha, l;
      if (d == fa) l = 1.f; else l = d/fa;
      float m_ = gt/ft;
      float t = 2.f - l;
      float mm2 = m_*m_, tt = t*t;
      float s = sqrtf(tt + mm2);
      float r_ = (l == 0.f) ? fabsf(m_) : sqrtf(l*l + mm2);
      float a = 0.5f*(s + r_);
      *ssmin = ha/a;
      *ssmax = fa*a;
      if (mm2 == 0.f) {
        if (l == 0.f) t = copysignf(2.f, ft)*copysignf(1.f, gt);
        else t = gt/copysignf(d, ft) + m_/t;
      } else {
        t = (m_/(s + t) + m_/(r_ + l))*(1.f + a);
      }
      float l2 = sqrtf(t*t + 4.f);
      crt = 2.f/l2;
      srt = t/l2;
      clt = (crt + srt*m_)/a;
      slt = (ht/ft)*srt/a;
    }
  }
  if (swap_) { *csl = srt; *snl = crt; *csr = slt; *snr = clt; }
  else { *csl = clt; *snl = slt; *csr = crt; *snr = srt; }
  float tsign = 1.f;
  if (pmax == 1) tsign = copysignf(1.f, *csr)*copysignf(1.f, *csl)*copysignf(1.f, f);
  if (pmax == 2) tsign = copysignf(1.f, *snr)*copysignf(1.f, *csl)*copysignf(1.f, g);
  if (pmax == 3) tsign = copysignf(1.f, *snr)*copysignf(1.f, *snl)*copysignf(1.f, h);
  *ssmax = copysignf(*ssmax, tsign);
  *ssmin = copysignf(*ssmin, tsign*copysignf(1.f, f)*copysignf(1.f, h));
}

// sbdsqr for n=9 upper bidiagonal, NCVT=9 (VT rotated), NRU=NCC=0, TOL>0.
__device__ void lap_bdsqr9(float* dd, float* ee, float VT[][9]) {
  const float eps_ = 5.9604645e-08f;
  const float unfl_ = 1.17549435e-38f;
  const float tol_ = 10.f*eps_;   // tolmul = max(10, min(100, eps^-1/8)) = 10
  const int n = 9;
  // init VT = I
  for (int i = 0; i < 9; ++i) for (int j = 0; j < 9; ++j) VT[i][j] = (i == j) ? 1.f : 0.f;
  float sminoa = fabsf(dd[0]);
  if (sminoa != 0.f) {
    float mu = sminoa;
    for (int i = 1; i < n; ++i) {
      mu = fabsf(dd[i])*(mu/(mu + fabsf(ee[i-1])));
      sminoa = fminf(sminoa, mu);
      if (sminoa == 0.f) break;
    }
  }
  sminoa = sminoa / 3.f;  // / sqrt(9)
  float thresh = fmaxf(tol_*sminoa, 486.f*unfl_);  // MAXITR*N*N*unfl
  int m = n, iter = 0, oldll = -1, oldm = -1, idir = 0;
  float sminl = 0.f;
  float rc[8], rs[8];
  int guard = 0;
  while (guard++ < 20000) {
    if (m <= 1) break;
    if (iter > 486) break;
    // --- find diagonal block ---
    float smax = fabsf(dd[m-1]);
    int ll = 0; bool split = false;
    for (int lll = 1; lll <= m - 1; ++lll) {
      int l2 = m - lll;
      float abss = fabsf(dd[l2-1]);
      float abse = fabsf(ee[l2-1]);
      if (abse <= thresh) { ll = l2; split = true; break; }
      smax = fmaxf(smax, fmaxf(abss, abse));
    }
    if (split) {
      ee[ll-1] = 0.f;
      if (ll == m - 1) { m = m - 1; continue; }
    } else ll = 0;
    ll = ll + 1;
    if (ll == m - 1) {
      // 2x2 block
      float sigmn, sigmx, sinr, cosr, sinl_, cosl_;
      lap_slasv2(dd[m-2], ee[m-2], dd[m-1], &sigmn, &sigmx, &sinr, &cosr, &sinl_, &cosl_);
      dd[m-2] = sigmx; ee[m-2] = 0.f; dd[m-1] = sigmn;
      for (int j = 0; j < 9; ++j) {
        float xt = VT[m-2][j], yt = VT[m-1][j];
        VT[m-2][j] = cosr*xt + sinr*yt;
        VT[m-1][j] = cosr*yt - sinr*xt;
      }
      m -= 2; continue;
    }
    if (ll > oldm || m < oldll) idir = (fabsf(dd[ll-1]) >= fabsf(dd[m-1])) ? 1 : 2;
    // --- convergence tests ---
    bool conv = false;
    if (idir == 1) {
      if (fabsf(ee[m-2]) <= tol_*fabsf(dd[m-1])) { ee[m-2] = 0.f; continue; }
      float mu = fabsf(dd[ll-1]);
      sminl = mu;
      for (int lll = ll; lll <= m - 1; ++lll) {
        if (fabsf(ee[lll-1]) <= tol_*mu) { ee[lll-1] = 0.f; conv = true; break; }
        mu = fabsf(dd[lll])*(mu/(mu + fabsf(ee[lll-1])));
        sminl = fminf(sminl, mu);
      }
    } else {
      if (fabsf(ee[ll-1]) <= tol_*fabsf(dd[ll-1])) { ee[ll-1] = 0.f; continue; }
      float mu = fabsf(dd[m-1]);
      sminl = mu;
      for (int lll = m - 1; lll >= ll; --lll) {
        if (fabsf(ee[lll-1]) <= tol_*mu) { ee[lll-1] = 0.f; conv = true; break; }
        mu = fabsf(dd[lll-1])*(mu/(mu + fabsf(ee[lll-1])));
        sminl = fminf(sminl, mu);
      }
    }
    if (conv) continue;
    oldll = ll; oldm = m;
    // --- shift ---
    float shift = 0.f, rdum;
    if (!((float)n*tol_*(sminl/smax) <= fmaxf(eps_, 0.01f*tol_))) {
      float sll;
      if (idir == 1) { sll = fabsf(dd[ll-1]); lap_slas2(dd[m-2], ee[m-2], dd[m-1], &shift, &rdum); }
      else           { sll = fabsf(dd[m-1]);  lap_slas2(dd[ll-1], ee[ll-1], dd[ll], &shift, &rdum); }
      if (sll > 0.f) { float q = shift/sll; if (q*q < eps_) shift = 0.f; }
    }
    iter += m - ll;
    if (shift == 0.f) {
      if (idir == 1) {
        float cs = 1.f, oldcs = 1.f, sn = 0.f, oldsn = 0.f, r;
        for (int i = ll; i <= m - 1; ++i) {
          lap_slartg(dd[i-1]*cs, ee[i-1], &cs, &sn, &r);
          if (i > ll) ee[i-2] = oldsn*r;
          float dn;
          lap_slartg(oldcs*r, dd[i]*sn, &oldcs, &oldsn, &dn);
          dd[i-1] = dn;
          rc[i-ll] = cs; rs[i-ll] = sn;
        }
        float h2 = dd[m-1]*cs;
        dd[m-1] = h2*oldcs;
        ee[m-2] = h2*oldsn;
        for (int k2 = 0; k2 <= m - ll - 1; ++k2) {
          int r0 = ll + k2 - 1;  // 0-based
          float c = rc[k2], s = rs[k2];
          for (int j = 0; j < 9; ++j) {
            float t = VT[r0+1][j];
            VT[r0+1][j] = c*t - s*VT[r0][j];
            VT[r0][j]   = s*t + c*VT[r0][j];
          }
        }
        if (fabsf(ee[m-2]) <= thresh) ee[m-2] = 0.f;
      } else {
        float cs = 1.f, oldcs = 1.f, sn = 0.f, oldsn = 0.f, r;
        for (int i = m; i >= ll + 1; --i) {
          lap_slartg(dd[i-1]*cs, ee[i-2], &cs, &sn, &r);
          if (i < m) ee[i-1] = oldsn*r;
          float dn;
          lap_slartg(oldcs*r, dd[i-2]*sn, &oldcs, &oldsn, &dn);
          dd[i-1] = dn;
          rc[i-ll-1] = oldcs; rs[i-ll-1] = -oldsn;
        }
        float h2 = dd[ll-1]*cs;
        dd[ll-1] = h2*oldcs;
        ee[ll-1] = h2*oldsn;
        for (int k2 = m - ll - 1; k2 >= 0; --k2) {
          int r0 = ll + k2 - 1;
          float c = rc[k2], s = rs[k2];
          for (int j = 0; j < 9; ++j) {
            float t = VT[r0+1][j];
            VT[r0+1][j] = c*t - s*VT[r0][j];
            VT[r0][j]   = s*t + c*VT[r0][j];
          }
        }
        if (fabsf(ee[ll-1]) <= thresh) ee[ll-1] = 0.f;
      }
    } else {
      if (idir == 1) {
        float f2 = (fabsf(dd[ll-1]) - shift)*(copysignf(1.f, dd[ll-1]) + shift/dd[ll-1]);
        float g2 = ee[ll-1];
        for (int i = ll; i <= m - 1; ++i) {
          float cr, sr, cl, sl, r;
          lap_slartg(f2, g2, &cr, &sr, &r);
          if (i > ll) ee[i-2] = r;
          f2 = cr*dd[i-1] + sr*ee[i-1];
          ee[i-1] = cr*ee[i-1] - sr*dd[i-1];
          g2 = sr*dd[i];
          dd[i] = cr*dd[i];
          lap_slartg(f2, g2, &cl, &sl, &r);
          dd[i-1] = r;
          f2 = cl*ee[i-1] + sl*dd[i];
          dd[i] = cl*dd[i] - sl*ee[i-1];
          if (i < m - 1) { g2 = sl*ee[i]; ee[i] = cl*ee[i]; }
          rc[i-ll] = cr; rs[i-ll] = sr;
        }
        ee[m-2] = f2;
        for (int k2 = 0; k2 <= m - ll - 1; ++k2) {
          int r0 = ll + k2 - 1;
          float c = rc[k2], s = rs[k2];
          for (int j = 0; j < 9; ++j) {
            float t = VT[r0+1][j];
            VT[r0+1][j] = c*t - s*VT[r0][j];
            VT[r0][j]   = s*t + c*VT[r0][j];
          }
        }
        if (fabsf(ee[m-2]) <= thresh) ee[m-2] = 0.f;
      } else {
        float f2 = (fabsf(dd[m-1]) - shift)*(copysignf(1.f, dd[m-1]) + shift/dd[m-1]);
        float g2 = ee[m-2];
        for (int i = m; i >= ll + 1; --i) {
          float cr, sr, cl, sl, r;
          lap_slartg(f2, g2, &cr, &sr, &r);
          if (i < m) ee[i-1] = r;
          f2 = cr*dd[i-1] + sr*ee[i-2];
          ee[i-2] = cr*ee[i-2] - sr*dd[i-1];
          g2 = sr*dd[i-2];
          dd[i-2] = cr*dd[i-2];
          lap_slartg(f2, g2, &cl, &sl, &r);
          dd[i-1] = r;
          f2 = cl*ee[i-2] + sl*dd[i-2];
          dd[i-2] = cl*dd[i-2] - sl*ee[i-2];
          if (i > ll + 1) { g2 = sl*ee[i-3]; ee[i-3] = cl*ee[i-3]; }
          rc[i-ll-1] = cl; rs[i-ll-1] = -sl;
        }
        ee[ll-1] = f2;
        if (fabsf(ee[ll-1]) <= thresh) ee[ll-1] = 0.f;
        for (int k2 = m - ll - 1; k2 >= 0; --k2) {
          int r0 = ll + k2 - 1;
          float c = rc[k2], s = rs[k2];
          for (int j = 0; j < 9; ++j) {
            float t = VT[r0+1][j];
            VT[r0+1][j] = c*t - s*VT[r0][j];
            VT[r0][j]   = s*t + c*VT[r0][j];
          }
        }
      }
    }
  }
  // make singular values positive
  for (int i = 0; i < n; ++i) {
    if (dd[i] < 0.f) {
      dd[i] = -dd[i];
      for (int j = 0; j < 9; ++j) VT[i][j] = -VT[i][j];
    }
  }
  // sort decreasing (LAPACK selection sort, one transposition per vector)
  for (int i = 1; i <= n - 1; ++i) {
    int isub = 1; float smin2 = dd[0];
    for (int j = 2; j <= n + 1 - i; ++j)
      if (dd[j-1] <= smin2) { isub = j; smin2 = dd[j-1]; }
    int tgt = n + 1 - i;
    if (isub != tgt) {
      dd[isub-1] = dd[tgt-1]; dd[tgt-1] = smin2;
      for (int j = 0; j < 9; ++j) {
        float t = VT[isub-1][j]; VT[isub-1][j] = VT[tgt-1][j]; VT[tgt-1][j] = t;
      }
    }
  }
}

// ---------------- SVD kernel: QR(1024x9) block-parallel, rest thread-0 -----
__global__ __launch_bounds__(256) void fm_svd(
    const float* __restrict__ Aglob, float* __restrict__ outH) {
  __shared__ float As[1024*9];
  __shared__ float red[256];
  __shared__ float bc[4];
  __shared__ float Rm[9][9], VT[9][9], PT[9][9];
  __shared__ float dd[9], ee[9], taup[9];
  int b = blockIdx.x, tid = threadIdx.x;
  const float* Ab = Aglob + (long)b*1024*9;
  for (int i = tid; i < 9216; i += 256) As[i] = Ab[i];
  __syncthreads();
  // Householder QR, LAPACK sgeqr2/slarfg conventions
  for (int k = 0; k < 9; ++k) {
    float ps = 0.f;
    for (int r = k + 1 + tid; r < 1024; r += 256) { float x = As[r*9 + k]; ps = fmaf(x, x, ps); }
    red[tid] = ps; __syncthreads();
    for (int off = 128; off > 0; off >>= 1) {
      if (tid < off) red[tid] += red[tid + off];
      __syncthreads();
    }
    if (tid == 0) {
      float ssq = red[0];
      float alpha = As[k*9 + k];
      float tau = 0.f, sc = 0.f, beta = alpha;
      if (ssq != 0.f) {
        beta = -copysignf(sqrtf(alpha*alpha + ssq), alpha);
        tau = (beta - alpha)/beta;
        sc = 1.f/(alpha - beta);
      }
      bc[0] = tau; bc[1] = sc; bc[2] = beta;
    }
    __syncthreads();
    float tau = bc[0], sc = bc[1];
    if (tau != 0.f) {
      for (int r = k + 1 + tid; r < 1024; r += 256) As[r*9 + k] *= sc;
    }
    __syncthreads();
    if (tau != 0.f) {
      for (int j = k + 1; j < 9; ++j) {
        float pd = 0.f;
        for (int r = k + 1 + tid; r < 1024; r += 256) pd = fmaf(As[r*9 + k], As[r*9 + j], pd);
        red[tid] = pd; __syncthreads();
        for (int off = 128; off > 0; off >>= 1) {
          if (tid < off) red[tid] += red[tid + off];
          __syncthreads();
        }
        float s = (red[0] + As[k*9 + j]) * tau;   // v_k = 1 at row k
        if (tid == 0) As[k*9 + j] -= s;
        for (int r = k + 1 + tid; r < 1024; r += 256) As[r*9 + j] -= s*As[r*9 + k];
        __syncthreads();
      }
    }
    if (tid == 0) As[k*9 + k] = bc[2];
    __syncthreads();
  }
  if (tid == 0) {
    // R (upper triangular 9x9)
    for (int i = 0; i < 9; ++i)
      for (int j = 0; j < 9; ++j)
        Rm[i][j] = (j >= i) ? As[i*9 + j] : 0.f;
    // --- sgebd2 on R ---
    for (int i = 0; i < 9; ++i) {
      // left reflector: col i, rows i..8
      float alpha = Rm[i][i];
      float ssq = 0.f;
      for (int r = i + 1; r < 9; ++r) ssq += Rm[r][i]*Rm[r][i];
      float tauq = 0.f, beta = alpha;
      if (ssq != 0.f) {
        beta = -copysignf(sqrtf(alpha*alpha + ssq), alpha);
        tauq = (beta - alpha)/beta;
        float sc = 1.f/(alpha - beta);
        for (int r = i + 1; r < 9; ++r) Rm[r][i] *= sc;
      }
      dd[i] = beta;
      if (tauq != 0.f) {
        for (int j = i + 1; j < 9; ++j) {
          float s = Rm[i][j];
          for (int r = i + 1; r < 9; ++r) s += Rm[r][i]*Rm[r][j];
          s *= tauq;
          Rm[i][j] -= s;
          for (int r = i + 1; r < 9; ++r) Rm[r][j] -= s*Rm[r][i];
        }
      }
      if (i < 8) {
        // right reflector: row i, cols i+1..8
        float alpha2 = Rm[i][i+1];
        float ssq2 = 0.f;
        for (int c = i + 2; c < 9; ++c) ssq2 += Rm[i][c]*Rm[i][c];
        float tp = 0.f, beta2 = alpha2;
        if (ssq2 != 0.f) {
          beta2 = -copysignf(sqrtf(alpha2*alpha2 + ssq2), alpha2);
          tp = (beta2 - alpha2)/beta2;
          float sc = 1.f/(alpha2 - beta2);
          for (int c = i + 2; c < 9; ++c) Rm[i][c] *= sc;
        }
        ee[i] = beta2;
        taup[i] = tp;
        if (tp != 0.f) {
          for (int r = i + 1; r < 9; ++r) {
            float s = Rm[r][i+1];
            for (int c = i + 2; c < 9; ++c) s += Rm[i][c]*Rm[r][c];
            s *= tp;
            Rm[r][i+1] -= s;
            for (int c = i + 2; c < 9; ++c) Rm[r][c] -= s*Rm[i][c];
          }
        }
      }
    }
    // --- PT = P^T = G_7 ... G_0 applied to I ---
    for (int i = 0; i < 9; ++i) for (int j = 0; j < 9; ++j) PT[i][j] = (i == j) ? 1.f : 0.f;
    for (int i = 0; i < 8; ++i) {
      float tp = taup[i];
      if (tp == 0.f) continue;
      for (int j = 0; j < 9; ++j) {
        float s = PT[i+1][j];
        for (int r = i + 2; r < 9; ++r) s += Rm[i][r]*PT[r][j];
        s *= tp;
        PT[i+1][j] -= s;
        for (int r = i + 2; r < 9; ++r) PT[r][j] -= s*Rm[i][r];
      }
    }
    // --- sbdsqr (VT of bidiagonal, sorted descending) ---
    lap_bdsqr9(dd, ee, VT);
    // --- H[i] = (VT * PT)[i][8] ---
    for (int i = 0; i < 9; ++i) {
      float s = 0.f;
      for (int k2 = 0; k2 < 9; ++k2) s += VT[i][k2]*PT[k2][8];
      outH[b*9 + i] = s;
    }
  }
}

// ===========================================================================
extern "C" void kernel_launch(void* const* d_in, const int* in_sizes, int n_in,
                              void* d_out, int out_size, void* d_ws, size_t ws_size,
                              hipStream_t stream) {
  const float* rgb  = (const float*)d_in[0];
  const float* ir   = (const float*)d_in[1];
  const float* w_dr = (const float*)d_in[2];
  const float* g_dr = (const float*)d_in[3];
  const float* b_dr = (const float*)d_in[4];
  const float* m_dr = (const float*)d_in[5];
  const float* v_dr = (const float*)d_in[6];
  const float* w_d1 = (const float*)d_in[7];
  const float* g_d1 = (const float*)d_in[8];
  const float* b_d1 = (const float*)d_in[9];
  const float* m_d1 = (const float*)d_in[10];
  const float* v_d1 = (const float*)d_in[11];
  const float* g_e  = (const float*)d_in[12];
  const float* b_e  = (const float*)d_in[13];
  const float* m_e  = (const float*)d_in[14];
  const float* v_e  = (const float*)d_in[15];
  const float* w_d2 = (const float*)d_in[16];
  const float* g_d2 = (const float*)d_in[17];
  const float* b_d2 = (const float*)d_in[18];
  const float* m_d2 = (const float*)d_in[19];
  const float* v_d2 = (const float*)d_in[20];

  float* out = (float*)d_out;
  float* ws  = (float*)d_ws;
  float* x1   = ws + OFF_X1;
  float* x2   = ws + OFF_X2;
  float* resp = ws + OFF_RESP;
  float* invn = ws + OFF_INVN;
  int*   topi = (int*)(ws + OFF_TOPI);
  float* wts  = ws + OFF_WTS;
  float* Amat = ws + OFF_A;

  fm_conv1<<<NIMG*128*16, 256, 0, stream>>>(rgb, ir, w_dr, g_dr, b_dr, m_dr, v_dr, x1);
  fm_conv3<<<NIMG*128*16, 256, 0, stream>>>(x1, w_d1, g_d1, b_d1, m_d1, v_d1,
                                            g_e, b_e, m_e, v_e, x2);
  fm_conv2<<<NIMG*64*16, 256, 0, stream>>>(x2, w_d2, g_d2, b_d2, m_d2, v_d2, out);
  fm_resp<<<(NIMG*HW4 + 255)/256, 256, 0, stream>>>(out, resp, invn);
  fm_sort<<<NIMG, 1024, 0, stream>>>(resp, topi);
  fm_wts<<<dim3(512, 2), 256, 0, stream>>>(out, invn, topi, wts);
  fm_build<<<4, 256, 0, stream>>>(topi, wts, Amat);
  fm_svd<<<2, 256, 0, stream>>>(Amat, out);
}

// Round 2
// 749.642 us; speedup vs baseline: 1.4437x; 1.4437x over previous
//
#include <hip/hip_runtime.h>
#include <math.h>

// ---------------------------------------------------------------------------
// FeatureMatching: conv tower -> top-k keypoints -> softmax corr gather ->
// weighted DLT -> LAPACK-faithful sgesdd(QR path) SVD for H = Vh[:,:,-1].
// All f32. B=2, C=256, H=W=64, HW=4096, K=512.
// R1: register-blocked convs (16 oc/block), weights in LDS, IC_STEP staging.
// ---------------------------------------------------------------------------

#define HW4 4096
#define NIMG 4   // imgs 0,1 = rgb batches; 2,3 = ir batches

// ws layout (floats)
#define OFF_X1   0L
#define OFF_X2   (OFF_X1 + 4L*128*4096)
#define OFF_RESP (OFF_X2 + 4L*128*4096)
#define OFF_INVN (OFF_RESP + 4L*4096)
#define OFF_TOPI (OFF_INVN + 4L*4096)      /* 4*512 ints */
#define OFF_WTS  (OFF_TOPI + 4L*512)
#define OFF_A    (OFF_WTS + 2L*512)

__device__ __forceinline__ float silu_f(float y) { return y / (1.f + expf(-y)); }

// ---------------- conv1: 1x1 256->128 + BN + SiLU (16 oc per block) --------
__global__ __launch_bounds__(256) void fm_conv1(
    const float* __restrict__ rgb, const float* __restrict__ ir,
    const float* __restrict__ w, const float* __restrict__ g,
    const float* __restrict__ bb, const float* __restrict__ mm,
    const float* __restrict__ vv, float* __restrict__ x1) {
  __shared__ float wl[256*16];   // [ic][o]
  int bid = blockIdx.x;
  int pblk = bid & 15, ocg = (bid >> 4) & 7, img = bid >> 7;
  int oc0 = ocg * 16;
  int tid = threadIdx.x;
  const float* src = (img < 2) ? (rgb + (long)img*256*HW4) : (ir + (long)(img-2)*256*HW4);
  for (int i = tid; i < 4096; i += 256) {
    int o = i & 15, ic = i >> 4;
    wl[i] = w[(oc0 + o)*256 + ic];
  }
  __syncthreads();
  int p = pblk*256 + tid;
  float acc[16];
  #pragma unroll
  for (int o = 0; o < 16; ++o) acc[o] = 0.f;
  #pragma unroll 4
  for (int ic = 0; ic < 256; ++ic) {
    float v = src[ic*HW4 + p];
    #pragma unroll
    for (int o = 0; o < 16; ++o) acc[o] = fmaf(wl[ic*16 + o], v, acc[o]);
  }
  #pragma unroll
  for (int o = 0; o < 16; ++o) {
    int oc = oc0 + o;
    float inv = 1.f / sqrtf(vv[oc] + 1e-5f);
    float y = (acc[o] - mm[oc]) * (g[oc]*inv) + bb[oc];
    x1[((long)img*128 + oc)*HW4 + p] = silu_f(y);
  }
}

// ---------------- conv3: 3x3 128->128 SAME + BN+SiLU + BN_e+ReLU -----------
// 16x16 px tile x 16 oc per block; 4 input channels staged per barrier.
#define C3_ICS 4
__global__ __launch_bounds__(256) void fm_conv3(
    const float* __restrict__ x1, const float* __restrict__ w,
    const float* __restrict__ g1, const float* __restrict__ b1,
    const float* __restrict__ m1, const float* __restrict__ v1,
    const float* __restrict__ ge, const float* __restrict__ be,
    const float* __restrict__ me, const float* __restrict__ ve,
    float* __restrict__ x2) {
  __shared__ float t[C3_ICS][18*18];
  __shared__ float wv[C3_ICS][16*9];
  int bid = blockIdx.x;
  int tile = bid & 15, ocg = (bid >> 4) & 7, img = bid >> 7;
  int oc0 = ocg * 16;
  int ty0 = (tile >> 2) * 16, tx0 = (tile & 3) * 16;
  int tid = threadIdx.x;
  int ly = tid >> 4, lx = tid & 15;
  float acc[16];
  #pragma unroll
  for (int o = 0; o < 16; ++o) acc[o] = 0.f;
  const float* xim = x1 + (long)img*128*HW4;
  for (int ic0 = 0; ic0 < 128; ic0 += C3_ICS) {
    // stage C3_ICS input tiles (18x18, zero-padded SAME border)
    for (int i = tid; i < C3_ICS*324; i += 256) {
      int q = i / 324, r = i - q*324;
      int ry = r / 18, rx = r - ry*18;
      int gy = ty0 + ry - 1, gx = tx0 + rx - 1;
      float val = 0.f;
      if (gy >= 0 && gy < 64 && gx >= 0 && gx < 64)
        val = xim[(long)(ic0 + q)*HW4 + gy*64 + gx];
      t[q][r] = val;
    }
    // stage weights: C3_ICS * 16 oc * 9
    for (int i = tid; i < C3_ICS*144; i += 256) {
      int q = i / 144, r = i - q*144;
      int o = r / 9, k = r - o*9;
      wv[q][r] = w[((long)(oc0 + o)*128 + ic0 + q)*9 + k];
    }
    __syncthreads();
    #pragma unroll
    for (int q = 0; q < C3_ICS; ++q) {
      float n0 = t[q][ly*18 + lx],     n1 = t[q][ly*18 + lx + 1],     n2 = t[q][ly*18 + lx + 2];
      float n3 = t[q][(ly+1)*18 + lx], n4 = t[q][(ly+1)*18 + lx + 1], n5 = t[q][(ly+1)*18 + lx + 2];
      float n6 = t[q][(ly+2)*18 + lx], n7 = t[q][(ly+2)*18 + lx + 1], n8 = t[q][(ly+2)*18 + lx + 2];
      #pragma unroll
      for (int o = 0; o < 16; ++o) {
        const float* wp = &wv[q][o*9];
        float a = acc[o];
        a = fmaf(wp[0], n0, a);
        a = fmaf(wp[1], n1, a);
        a = fmaf(wp[2], n2, a);
        a = fmaf(wp[3], n3, a);
        a = fmaf(wp[4], n4, a);
        a = fmaf(wp[5], n5, a);
        a = fmaf(wp[6], n6, a);
        a = fmaf(wp[7], n7, a);
        a = fmaf(wp[8], n8, a);
        acc[o] = a;
      }
    }
    __syncthreads();
  }
  int p = (ty0 + ly)*64 + tx0 + lx;
  #pragma unroll
  for (int o = 0; o < 16; ++o) {
    int oc = oc0 + o;
    float inv1 = 1.f / sqrtf(v1[oc] + 1e-5f);
    float y = (acc[o] - m1[oc]) * (g1[oc]*inv1) + b1[oc];
    y = silu_f(y);
    float inve = 1.f / sqrtf(ve[oc] + 1e-5f);
    float z = (y - me[oc]) * (ge[oc]*inve) + be[oc];
    z = fmaxf(z, 0.f);
    x2[((long)img*128 + oc)*HW4 + p] = z;
  }
}

// ---------------- conv2: 1x1 128->64 + BN + SiLU -> desc (into d_out) ------
__global__ __launch_bounds__(256) void fm_conv2(
    const float* __restrict__ x2, const float* __restrict__ w,
    const float* __restrict__ g, const float* __restrict__ bb,
    const float* __restrict__ mm, const float* __restrict__ vv,
    float* __restrict__ out) {
  __shared__ float wl[128*16];   // [ic][o]
  int bid = blockIdx.x;
  int pblk = bid & 15, ocg = (bid >> 4) & 3, img = bid >> 6;
  int oc0 = ocg * 16;
  int tid = threadIdx.x;
  for (int i = tid; i < 2048; i += 256) {
    int o = i & 15, ic = i >> 4;
    wl[i] = w[(oc0 + o)*128 + ic];
  }
  __syncthreads();
  int p = pblk*256 + tid;
  const float* src = x2 + (long)img*128*HW4;
  float acc[16];
  #pragma unroll
  for (int o = 0; o < 16; ++o) acc[o] = 0.f;
  #pragma unroll 4
  for (int ic = 0; ic < 128; ++ic) {
    float v = src[ic*HW4 + p];
    #pragma unroll
    for (int o = 0; o < 16; ++o) acc[o] = fmaf(wl[ic*16 + o], v, acc[o]);
  }
  #pragma unroll
  for (int o = 0; o < 16; ++o) {
    int oc = oc0 + o;
    float inv = 1.f / sqrtf(vv[oc] + 1e-5f);
    float y = (acc[o] - mm[oc]) * (g[oc]*inv) + bb[oc];
    out[18 + (long)img*262144 + oc*HW4 + p] = silu_f(y);
  }
}

// ---------------- resp + inv-norm ----------------
__global__ __launch_bounds__(256) void fm_resp(
    const float* __restrict__ out, float* __restrict__ resp, float* __restrict__ invn) {
  int t = blockIdx.x*256 + threadIdx.x;
  if (t >= NIMG*HW4) return;
  int img = t >> 12, p = t & 4095;
  const float* d = out + 18 + (long)img*262144;
  float s = 0.f;
  #pragma unroll
  for (int c = 0; c < 64; ++c) { float x = d[c*HW4 + p]; s = fmaf(x, x, s); }
  float r = sqrtf(s);
  resp[t] = r;
  invn[t] = 1.f / fmaxf(r, 1e-12f);
}

// ---------------- top-512 via full bitonic sort (desc value, asc index) ----
__global__ __launch_bounds__(1024) void fm_sort(
    const float* __restrict__ resp, int* __restrict__ topidx) {
  __shared__ unsigned long long keys[4096];
  int img = blockIdx.x, tid = threadIdx.x;
  const float* r = resp + (long)img*HW4;
  for (int i = tid; i < 4096; i += 1024) {
    unsigned int vb = __float_as_uint(r[i]);   // resp >= 0 -> bits monotone
    keys[i] = ((unsigned long long)vb << 32) | (unsigned int)(4095 - i);
  }
  __syncthreads();
  for (int k = 2; k <= 4096; k <<= 1) {
    for (int j = k >> 1; j > 0; j >>= 1) {
      for (int t = tid; t < 2048; t += 1024) {
        int i = 2*t - (t & (j - 1));
        int ixj = i ^ j;
        bool up = ((i & k) == 0);
        unsigned long long a = keys[i], b = keys[ixj];
        if ((a < b) == up) { keys[i] = b; keys[ixj] = a; }
      }
      __syncthreads();
    }
  }
  if (tid < 512) topidx[img*512 + tid] = 4095 - (int)(keys[tid] & 0xFFFFFFFFull);
}

// ---------------- softmax-weight gather (one block per keypoint) -----------
__global__ __launch_bounds__(256) void fm_wts(
    const float* __restrict__ out, const float* __restrict__ invn,
    const int* __restrict__ topidx, float* __restrict__ wts) {
  int kq = blockIdx.x, b = blockIdx.y, tid = threadIdx.x;
  const float* d1 = out + 18 + (long)b*262144;
  const float* d2 = out + 18 + (long)(2 + b)*262144;
  const float* in1 = invn + (long)b*HW4;
  const float* in2 = invn + (long)(2 + b)*HW4;
  int row = topidx[b*512 + kq];
  int col = topidx[(2 + b)*512 + kq];
  __shared__ float q[64];
  if (tid < 64) q[tid] = d1[tid*HW4 + row] * in1[row];
  __syncthreads();
  float mloc = -INFINITY, sloc = 0.f;
  for (int j = tid; j < 4096; j += 256) {
    float dot = 0.f;
    #pragma unroll
    for (int c = 0; c < 64; ++c) dot = fmaf(q[c], d2[c*HW4 + j], dot);
    float v = dot * in2[j];
    if (v > mloc) { sloc = sloc*expf(mloc - v) + 1.f; mloc = v; }
    else sloc += expf(v - mloc);
  }
  __shared__ float sm[256], ss[256];
  sm[tid] = mloc; ss[tid] = sloc;
  __syncthreads();
  for (int off = 128; off > 0; off >>= 1) {
    if (tid < off) {
      float m1 = sm[tid], m2 = sm[tid + off];
      float M = fmaxf(m1, m2);
      ss[tid] = ss[tid]*expf(m1 - M) + ss[tid + off]*expf(m2 - M);
      sm[tid] = M;
    }
    __syncthreads();
  }
  if (tid == 0) {
    float dot = 0.f;
    for (int c = 0; c < 64; ++c) dot = fmaf(q[c], d2[c*HW4 + col], dot);
    float v = dot * in2[col];
    wts[b*512 + kq] = expf(v - sm[0]) / ss[0];
  }
}

// ---------------- build DLT rows ----------------
__global__ __launch_bounds__(256) void fm_build(
    const int* __restrict__ topidx, const float* __restrict__ wts,
    float* __restrict__ A) {
  int t = blockIdx.x*256 + threadIdx.x;
  if (t >= 1024) return;
  int b = t >> 9, k = t & 511;
  int i1 = topidx[b*512 + k], i2 = topidx[(2 + b)*512 + k];
  float w = wts[b*512 + k];
  float x1 = (float)(i1 & 63) / 63.f * 2.f - 1.f;
  float y1 = (float)(i1 >> 6) / 63.f * 2.f - 1.f;
  float x2 = (float)(i2 & 63) / 63.f * 2.f - 1.f;
  float y2 = (float)(i2 >> 6) / 63.f * 2.f - 1.f;
  float* r = A + ((long)b*1024 + 2*k)*9;
  r[0] = x1*w;  r[1] = y1*w;  r[2] = w;
  r[3] = 0.f;   r[4] = 0.f;   r[5] = 0.f;
  r[6] = (-x2*x1)*w; r[7] = (-x2*y1)*w; r[8] = (-x2)*w;
  r[9]  = 0.f;  r[10] = 0.f;  r[11] = 0.f;
  r[12] = x1*w; r[13] = y1*w; r[14] = w;
  r[15] = (-y2*x1)*w; r[16] = (-y2*y1)*w; r[17] = (-y2)*w;
}

// =========================== LAPACK ports ===================================
// slartg, LAPACK >= 3.10 convention: c >= 0, r = sign(f)*hypot.
__device__ void lap_slartg(float f, float g, float* cs, float* sn, float* r) {
  if (g == 0.f) { *cs = 1.f; *sn = 0.f; *r = f; }
  else if (f == 0.f) { *cs = 0.f; *sn = copysignf(1.f, g); *r = fabsf(g); }
  else {
    float d = sqrtf(f*f + g*g);
    *cs = fabsf(f) / d;
    *r = copysignf(d, f);
    *sn = g / (*r);
  }
}

__device__ void lap_slas2(float f, float g, float h, float* ssmin, float* ssmax) {
  float fa = fabsf(f), ga = fabsf(g), ha = fabsf(h);
  float fhmn = fminf(fa, ha), fhmx = fmaxf(fa, ha);
  if (fhmn == 0.f) {
    *ssmin = 0.f;
    if (fhmx == 0.f) *ssmax = ga;
    else {
      float mx = fmaxf(fhmx, ga), mn = fminf(fhmx, ga);
      float q = mn / mx;
      *ssmax = mx * sqrtf(1.f + q*q);
    }
  } else {
    if (ga < fhmx) {
      float as_ = 1.f + fhmn/fhmx;
      float at_ = (fhmx - fhmn)/fhmx;
      float au = ga/fhmx; au = au*au;
      float c = 2.f / (sqrtf(as_*as_ + au) + sqrtf(at_*at_ + au));
      *ssmin = fhmn*c;
      *ssmax = fhmx/c;
    } else {
      float au = fhmx/ga;
      if (au == 0.f) { *ssmin = (fhmn*fhmx)/ga; *ssmax = ga; }
      else {
        float as_ = 1.f + fhmn/fhmx;
        float at_ = (fhmx - fhmn)/fhmx;
        float t1 = as_*au, t2 = at_*au;
        float c = 1.f / (sqrtf(1.f + t1*t1) + sqrtf(1.f + t2*t2));
        float smn = (fhmn*c)*au;
        *ssmin = smn + smn;
        *ssmax = ga/(c + c);
      }
    }
  }
}

__device__ void lap_slasv2(float f, float g, float h, float* ssmin, float* ssmax,
                           float* snr, float* csr, float* snl, float* csl) {
  const float epsv = 5.9604645e-08f;
  float ft = f, fa = fabsf(f), ht = h, ha = fabsf(h);
  int pmax = 1;
  bool swap_ = (ha > fa);
  if (swap_) { pmax = 3; float tmp = ft; ft = ht; ht = tmp; tmp = fa; fa = ha; ha = tmp; }
  float gt = g, ga = fabsf(gt);
  float clt = 0.f, crt = 0.f, slt = 0.f, srt = 0.f;
  if (ga == 0.f) { *ssmin = ha; *ssmax = fa; clt = 1.f; crt = 1.f; slt = 0.f; srt = 0.f; }
  else {
    bool gasmal = true;
    if (ga > fa) {
      pmax = 2;
      if ((fa/ga) < epsv) {
        gasmal = false;
        *ssmax = ga;
        if (ha > 1.f) *ssmin = fa/(ga/ha); else *ssmin = (fa/ga)*ha;
        clt = 1.f; slt = ht/gt; srt = 1.f; crt = ft/gt;
      }
    }
    if (gasmal) {
      float d = fa - ha, l;
      if (d == fa) l = 1.f; else l = d/fa;
      float m_ = gt/ft;
      float t = 2.f - l;
      float mm2 = m_*m_, tt = t*t;
      float s = sqrtf(tt + mm2);
      float r_ = (l == 0.f) ? fabsf(m_) : sqrtf(l*l + mm2);
      float a = 0.5f*(s + r_);
      *ssmin = ha/a;
      *ssmax = fa*a;
      if (mm2 == 0.f) {
        if (l == 0.f) t = copysignf(2.f, ft)*copysignf(1.f, gt);
        else t = gt/copysignf(d, ft) + m_/t;
      } else {
        t = (m_/(s + t) + m_/(r_ + l))*(1.f + a);
      }
      float l2 = sqrtf(t*t + 4.f);
      crt = 2.f/l2;
      srt = t/l2;
      clt = (crt + srt*m_)/a;
      slt = (ht/ft)*srt/a;
    }
  }
  if (swap_) { *csl = srt; *snl = crt; *csr = slt; *snr = clt; }
  else { *csl = clt; *snl = slt; *csr = crt; *snr = srt; }
  float tsign = 1.f;
  if (pmax == 1) tsign = copysignf(1.f, *csr)*copysignf(1.f, *csl)*copysignf(1.f, f);
  if (pmax == 2) tsign = copysignf(1.f, *snr)*copysignf(1.f, *csl)*copysignf(1.f, g);
  if (pmax == 3) tsign = copysignf(1.f, *snr)*copysignf(1.f, *snl)*copysignf(1.f, h);
  *ssmax = copysignf(*ssmax, tsign);
  *ssmin = copysignf(*ssmin, tsign*copysignf(1.f, f)*copysignf(1.f, h));
}

// sbdsqr for n=9 upper bidiagonal, NCVT=9 (VT rotated), NRU=NCC=0, TOL>0.
__device__ void lap_bdsqr9(float* dd, float* ee, float VT[][9]) {
  const float eps_ = 5.9604645e-08f;
  const float unfl_ = 1.17549435e-38f;
  const float tol_ = 10.f*eps_;   // tolmul = max(10, min(100, eps^-1/8)) = 10
  const int n = 9;
  // init VT = I
  for (int i = 0; i < 9; ++i) for (int j = 0; j < 9; ++j) VT[i][j] = (i == j) ? 1.f : 0.f;
  float sminoa = fabsf(dd[0]);
  if (sminoa != 0.f) {
    float mu = sminoa;
    for (int i = 1; i < n; ++i) {
      mu = fabsf(dd[i])*(mu/(mu + fabsf(ee[i-1])));
      sminoa = fminf(sminoa, mu);
      if (sminoa == 0.f) break;
    }
  }
  sminoa = sminoa / 3.f;  // / sqrt(9)
  float thresh = fmaxf(tol_*sminoa, 486.f*unfl_);  // MAXITR*N*N*unfl
  int m = n, iter = 0, oldll = -1, oldm = -1, idir = 0;
  float sminl = 0.f;
  float rc[8], rs[8];
  int guard = 0;
  while (guard++ < 20000) {
    if (m <= 1) break;
    if (iter > 486) break;
    // --- find diagonal block ---
    float smax = fabsf(dd[m-1]);
    int ll = 0; bool split = false;
    for (int lll = 1; lll <= m - 1; ++lll) {
      int l2 = m - lll;
      float abss = fabsf(dd[l2-1]);
      float abse = fabsf(ee[l2-1]);
      if (abse <= thresh) { ll = l2; split = true; break; }
      smax = fmaxf(smax, fmaxf(abss, abse));
    }
    if (split) {
      ee[ll-1] = 0.f;
      if (ll == m - 1) { m = m - 1; continue; }
    } else ll = 0;
    ll = ll + 1;
    if (ll == m - 1) {
      // 2x2 block
      float sigmn, sigmx, sinr, cosr, sinl_, cosl_;
      lap_slasv2(dd[m-2], ee[m-2], dd[m-1], &sigmn, &sigmx, &sinr, &cosr, &sinl_, &cosl_);
      dd[m-2] = sigmx; ee[m-2] = 0.f; dd[m-1] = sigmn;
      for (int j = 0; j < 9; ++j) {
        float xt = VT[m-2][j], yt = VT[m-1][j];
        VT[m-2][j] = cosr*xt + sinr*yt;
        VT[m-1][j] = cosr*yt - sinr*xt;
      }
      m -= 2; continue;
    }
    if (ll > oldm || m < oldll) idir = (fabsf(dd[ll-1]) >= fabsf(dd[m-1])) ? 1 : 2;
    // --- convergence tests ---
    bool conv = false;
    if (idir == 1) {
      if (fabsf(ee[m-2]) <= tol_*fabsf(dd[m-1])) { ee[m-2] = 0.f; continue; }
      float mu = fabsf(dd[ll-1]);
      sminl = mu;
      for (int lll = ll; lll <= m - 1; ++lll) {
        if (fabsf(ee[lll-1]) <= tol_*mu) { ee[lll-1] = 0.f; conv = true; break; }
        mu = fabsf(dd[lll])*(mu/(mu + fabsf(ee[lll-1])));
        sminl = fminf(sminl, mu);
      }
    } else {
      if (fabsf(ee[ll-1]) <= tol_*fabsf(dd[ll-1])) { ee[ll-1] = 0.f; continue; }
      float mu = fabsf(dd[m-1]);
      sminl = mu;
      for (int lll = m - 1; lll >= ll; --lll) {
        if (fabsf(ee[lll-1]) <= tol_*mu) { ee[lll-1] = 0.f; conv = true; break; }
        mu = fabsf(dd[lll-1])*(mu/(mu + fabsf(ee[lll-1])));
        sminl = fminf(sminl, mu);
      }
    }
    if (conv) continue;
    oldll = ll; oldm = m;
    // --- shift ---
    float shift = 0.f, rdum;
    if (!((float)n*tol_*(sminl/smax) <= fmaxf(eps_, 0.01f*tol_))) {
      float sll;
      if (idir == 1) { sll = fabsf(dd[ll-1]); lap_slas2(dd[m-2], ee[m-2], dd[m-1], &shift, &rdum); }
      else           { sll = fabsf(dd[m-1]);  lap_slas2(dd[ll-1], ee[ll-1], dd[ll], &shift, &rdum); }
      if (sll > 0.f) { float q = shift/sll; if (q*q < eps_) shift = 0.f; }
    }
    iter += m - ll;
    if (shift == 0.f) {
      if (idir == 1) {
        float cs = 1.f, oldcs = 1.f, sn = 0.f, oldsn = 0.f, r;
        for (int i = ll; i <= m - 1; ++i) {
          lap_slartg(dd[i-1]*cs, ee[i-1], &cs, &sn, &r);
          if (i > ll) ee[i-2] = oldsn*r;
          float dn;
          lap_slartg(oldcs*r, dd[i]*sn, &oldcs, &oldsn, &dn);
          dd[i-1] = dn;
          rc[i-ll] = cs; rs[i-ll] = sn;
        }
        float h2 = dd[m-1]*cs;
        dd[m-1] = h2*oldcs;
        ee[m-2] = h2*oldsn;
        for (int k2 = 0; k2 <= m - ll - 1; ++k2) {
          int r0 = ll + k2 - 1;  // 0-based
          float c = rc[k2], s = rs[k2];
          for (int j = 0; j < 9; ++j) {
            float t = VT[r0+1][j];
            VT[r0+1][j] = c*t - s*VT[r0][j];
            VT[r0][j]   = s*t + c*VT[r0][j];
          }
        }
        if (fabsf(ee[m-2]) <= thresh) ee[m-2] = 0.f;
      } else {
        float cs = 1.f, oldcs = 1.f, sn = 0.f, oldsn = 0.f, r;
        for (int i = m; i >= ll + 1; --i) {
          lap_slartg(dd[i-1]*cs, ee[i-2], &cs, &sn, &r);
          if (i < m) ee[i-1] = oldsn*r;
          float dn;
          lap_slartg(oldcs*r, dd[i-2]*sn, &oldcs, &oldsn, &dn);
          dd[i-1] = dn;
          rc[i-ll-1] = oldcs; rs[i-ll-1] = -oldsn;
        }
        float h2 = dd[ll-1]*cs;
        dd[ll-1] = h2*oldcs;
        ee[ll-1] = h2*oldsn;
        for (int k2 = m - ll - 1; k2 >= 0; --k2) {
          int r0 = ll + k2 - 1;
          float c = rc[k2], s = rs[k2];
          for (int j = 0; j < 9; ++j) {
            float t = VT[r0+1][j];
            VT[r0+1][j] = c*t - s*VT[r0][j];
            VT[r0][j]   = s*t + c*VT[r0][j];
          }
        }
        if (fabsf(ee[ll-1]) <= thresh) ee[ll-1] = 0.f;
      }
    } else {
      if (idir == 1) {
        float f2 = (fabsf(dd[ll-1]) - shift)*(copysignf(1.f, dd[ll-1]) + shift/dd[ll-1]);
        float g2 = ee[ll-1];
        for (int i = ll; i <= m - 1; ++i) {
          float cr, sr, cl, sl, r;
          lap_slartg(f2, g2, &cr, &sr, &r);
          if (i > ll) ee[i-2] = r;
          f2 = cr*dd[i-1] + sr*ee[i-1];
          ee[i-1] = cr*ee[i-1] - sr*dd[i-1];
          g2 = sr*dd[i];
          dd[i] = cr*dd[i];
          lap_slartg(f2, g2, &cl, &sl, &r);
          dd[i-1] = r;
          f2 = cl*ee[i-1] + sl*dd[i];
          dd[i] = cl*dd[i] - sl*ee[i-1];
          if (i < m - 1) { g2 = sl*ee[i]; ee[i] = cl*ee[i]; }
          rc[i-ll] = cr; rs[i-ll] = sr;
        }
        ee[m-2] = f2;
        for (int k2 = 0; k2 <= m - ll - 1; ++k2) {
          int r0 = ll + k2 - 1;
          float c = rc[k2], s = rs[k2];
          for (int j = 0; j < 9; ++j) {
            float t = VT[r0+1][j];
            VT[r0+1][j] = c*t - s*VT[r0][j];
            VT[r0][j]   = s*t + c*VT[r0][j];
          }
        }
        if (fabsf(ee[m-2]) <= thresh) ee[m-2] = 0.f;
      } else {
        float f2 = (fabsf(dd[m-1]) - shift)*(copysignf(1.f, dd[m-1]) + shift/dd[m-1]);
        float g2 = ee[m-2];
        for (int i = m; i >= ll + 1; --i) {
          float cr, sr, cl, sl, r;
          lap_slartg(f2, g2, &cr, &sr, &r);
          if (i < m) ee[i-1] = r;
          f2 = cr*dd[i-1] + sr*ee[i-2];
          ee[i-2] = cr*ee[i-2] - sr*dd[i-1];
          g2 = sr*dd[i-2];
          dd[i-2] = cr*dd[i-2];
          lap_slartg(f2, g2, &cl, &sl, &r);
          dd[i-1] = r;
          f2 = cl*ee[i-2] + sl*dd[i-2];
          dd[i-2] = cl*dd[i-2] - sl*ee[i-2];
          if (i > ll + 1) { g2 = sl*ee[i-3]; ee[i-3] = cl*ee[i-3]; }
          rc[i-ll-1] = cl; rs[i-ll-1] = -sl;
        }
        ee[ll-1] = f2;
        if (fabsf(ee[ll-1]) <= thresh) ee[ll-1] = 0.f;
        for (int k2 = m - ll - 1; k2 >= 0; --k2) {
          int r0 = ll + k2 - 1;
          float c = rc[k2], s = rs[k2];
          for (int j = 0; j < 9; ++j) {
            float t = VT[r0+1][j];
            VT[r0+1][j] = c*t - s*VT[r0][j];
            VT[r0][j]   = s*t + c*VT[r0][j];
          }
        }
      }
    }
  }
  // make singular values positive
  for (int i = 0; i < n; ++i) {
    if (dd[i] < 0.f) {
      dd[i] = -dd[i];
      for (int j = 0; j < 9; ++j) VT[i][j] = -VT[i][j];
    }
  }
  // sort decreasing (LAPACK selection sort, one transposition per vector)
  for (int i = 1; i <= n - 1; ++i) {
    int isub = 1; float smin2 = dd[0];
    for (int j = 2; j <= n + 1 - i; ++j)
      if (dd[j-1] <= smin2) { isub = j; smin2 = dd[j-1]; }
    int tgt = n + 1 - i;
    if (isub != tgt) {
      dd[isub-1] = dd[tgt-1]; dd[tgt-1] = smin2;
      for (int j = 0; j < 9; ++j) {
        float t = VT[isub-1][j]; VT[isub-1][j] = VT[tgt-1][j]; VT[tgt-1][j] = t;
      }
    }
  }
}

// ---------------- SVD kernel: QR(1024x9) block-parallel, rest thread-0 -----
__global__ __launch_bounds__(256) void fm_svd(
    const float* __restrict__ Aglob, float* __restrict__ outH) {
  __shared__ float As[1024*9];
  __shared__ float red[256];
  __shared__ float bc[4];
  __shared__ float Rm[9][9], VT[9][9], PT[9][9];
  __shared__ float dd[9], ee[9], taup[9];
  int b = blockIdx.x, tid = threadIdx.x;
  const float* Ab = Aglob + (long)b*1024*9;
  for (int i = tid; i < 9216; i += 256) As[i] = Ab[i];
  __syncthreads();
  // Householder QR, LAPACK sgeqr2/slarfg conventions
  for (int k = 0; k < 9; ++k) {
    float ps = 0.f;
    for (int r = k + 1 + tid; r < 1024; r += 256) { float x = As[r*9 + k]; ps = fmaf(x, x, ps); }
    red[tid] = ps; __syncthreads();
    for (int off = 128; off > 0; off >>= 1) {
      if (tid < off) red[tid] += red[tid + off];
      __syncthreads();
    }
    if (tid == 0) {
      float ssq = red[0];
      float alpha = As[k*9 + k];
      float tau = 0.f, sc = 0.f, beta = alpha;
      if (ssq != 0.f) {
        beta = -copysignf(sqrtf(alpha*alpha + ssq), alpha);
        tau = (beta - alpha)/beta;
        sc = 1.f/(alpha - beta);
      }
      bc[0] = tau; bc[1] = sc; bc[2] = beta;
    }
    __syncthreads();
    float tau = bc[0], sc = bc[1];
    if (tau != 0.f) {
      for (int r = k + 1 + tid; r < 1024; r += 256) As[r*9 + k] *= sc;
    }
    __syncthreads();
    if (tau != 0.f) {
      for (int j = k + 1; j < 9; ++j) {
        float pd = 0.f;
        for (int r = k + 1 + tid; r < 1024; r += 256) pd = fmaf(As[r*9 + k], As[r*9 + j], pd);
        red[tid] = pd; __syncthreads();
        for (int off = 128; off > 0; off >>= 1) {
          if (tid < off) red[tid] += red[tid + off];
          __syncthreads();
        }
        float s = (red[0] + As[k*9 + j]) * tau;   // v_k = 1 at row k
        if (tid == 0) As[k*9 + j] -= s;
        for (int r = k + 1 + tid; r < 1024; r += 256) As[r*9 + j] -= s*As[r*9 + k];
        __syncthreads();
      }
    }
    if (tid == 0) As[k*9 + k] = bc[2];
    __syncthreads();
  }
  if (tid == 0) {
    // R (upper triangular 9x9)
    for (int i = 0; i < 9; ++i)
      for (int j = 0; j < 9; ++j)
        Rm[i][j] = (j >= i) ? As[i*9 + j] : 0.f;
    // --- sgebd2 on R ---
    for (int i = 0; i < 9; ++i) {
      // left reflector: col i, rows i..8
      float alpha = Rm[i][i];
      float ssq = 0.f;
      for (int r = i + 1; r < 9; ++r) ssq += Rm[r][i]*Rm[r][i];
      float tauq = 0.f, beta = alpha;
      if (ssq != 0.f) {
        beta = -copysignf(sqrtf(alpha*alpha + ssq), alpha);
        tauq = (beta - alpha)/beta;
        float sc = 1.f/(alpha - beta);
        for (int r = i + 1; r < 9; ++r) Rm[r][i] *= sc;
      }
      dd[i] = beta;
      if (tauq != 0.f) {
        for (int j = i + 1; j < 9; ++j) {
          float s = Rm[i][j];
          for (int r = i + 1; r < 9; ++r) s += Rm[r][i]*Rm[r][j];
          s *= tauq;
          Rm[i][j] -= s;
          for (int r = i + 1; r < 9; ++r) Rm[r][j] -= s*Rm[r][i];
        }
      }
      if (i < 8) {
        // right reflector: row i, cols i+1..8
        float alpha2 = Rm[i][i+1];
        float ssq2 = 0.f;
        for (int c = i + 2; c < 9; ++c) ssq2 += Rm[i][c]*Rm[i][c];
        float tp = 0.f, beta2 = alpha2;
        if (ssq2 != 0.f) {
          beta2 = -copysignf(sqrtf(alpha2*alpha2 + ssq2), alpha2);
          tp = (beta2 - alpha2)/beta2;
          float sc = 1.f/(alpha2 - beta2);
          for (int c = i + 2; c < 9; ++c) Rm[i][c] *= sc;
        }
        ee[i] = beta2;
        taup[i] = tp;
        if (tp != 0.f) {
          for (int r = i + 1; r < 9; ++r) {
            float s = Rm[r][i+1];
            for (int c = i + 2; c < 9; ++c) s += Rm[i][c]*Rm[r][c];
            s *= tp;
            Rm[r][i+1] -= s;
            for (int c = i + 2; c < 9; ++c) Rm[r][c] -= s*Rm[i][c];
          }
        }
      }
    }
    // --- PT = P^T = G_7 ... G_0 applied to I ---
    for (int i = 0; i < 9; ++i) for (int j = 0; j < 9; ++j) PT[i][j] = (i == j) ? 1.f : 0.f;
    for (int i = 0; i < 8; ++i) {
      float tp = taup[i];
      if (tp == 0.f) continue;
      for (int j = 0; j < 9; ++j) {
        float s = PT[i+1][j];
        for (int r = i + 2; r < 9; ++r) s += Rm[i][r]*PT[r][j];
        s *= tp;
        PT[i+1][j] -= s;
        for (int r = i + 2; r < 9; ++r) PT[r][j] -= s*Rm[i][r];
      }
    }
    // --- sbdsqr (VT of bidiagonal, sorted descending) ---
    lap_bdsqr9(dd, ee, VT);
    // --- H[i] = (VT * PT)[i][8] ---
    for (int i = 0; i < 9; ++i) {
      float s = 0.f;
      for (int k2 = 0; k2 < 9; ++k2) s += VT[i][k2]*PT[k2][8];
      outH[b*9 + i] = s;
    }
  }
}

// ===========================================================================
extern "C" void kernel_launch(void* const* d_in, const int* in_sizes, int n_in,
                              void* d_out, int out_size, void* d_ws, size_t ws_size,
                              hipStream_t stream) {
  const float* rgb  = (const float*)d_in[0];
  const float* ir   = (const float*)d_in[1];
  const float* w_dr = (const float*)d_in[2];
  const float* g_dr = (const float*)d_in[3];
  const float* b_dr = (const float*)d_in[4];
  const float* m_dr = (const float*)d_in[5];
  const float* v_dr = (const float*)d_in[6];
  const float* w_d1 = (const float*)d_in[7];
  const float* g_d1 = (const float*)d_in[8];
  const float* b_d1 = (const float*)d_in[9];
  const float* m_d1 = (const float*)d_in[10];
  const float* v_d1 = (const float*)d_in[11];
  const float* g_e  = (const float*)d_in[12];
  const float* b_e  = (const float*)d_in[13];
  const float* m_e  = (const float*)d_in[14];
  const float* v_e  = (const float*)d_in[15];
  const float* w_d2 = (const float*)d_in[16];
  const float* g_d2 = (const float*)d_in[17];
  const float* b_d2 = (const float*)d_in[18];
  const float* m_d2 = (const float*)d_in[19];
  const float* v_d2 = (const float*)d_in[20];

  float* out = (float*)d_out;
  float* ws  = (float*)d_ws;
  float* x1   = ws + OFF_X1;
  float* x2   = ws + OFF_X2;
  float* resp = ws + OFF_RESP;
  float* invn = ws + OFF_INVN;
  int*   topi = (int*)(ws + OFF_TOPI);
  float* wts  = ws + OFF_WTS;
  float* Amat = ws + OFF_A;

  fm_conv1<<<NIMG*8*16, 256, 0, stream>>>(rgb, ir, w_dr, g_dr, b_dr, m_dr, v_dr, x1);
  fm_conv3<<<NIMG*8*16, 256, 0, stream>>>(x1, w_d1, g_d1, b_d1, m_d1, v_d1,
                                          g_e, b_e, m_e, v_e, x2);
  fm_conv2<<<NIMG*4*16, 256, 0, stream>>>(x2, w_d2, g_d2, b_d2, m_d2, v_d2, out);
  fm_resp<<<(NIMG*HW4 + 255)/256, 256, 0, stream>>>(out, resp, invn);
  fm_sort<<<NIMG, 1024, 0, stream>>>(resp, topi);
  fm_wts<<<dim3(512, 2), 256, 0, stream>>>(out, invn, topi, wts);
  fm_build<<<4, 256, 0, stream>>>(topi, wts, Amat);
  fm_svd<<<2, 256, 0, stream>>>(Amat, out);
}

// Round 3
// 535.501 us; speedup vs baseline: 2.0210x; 1.3999x over previous
//
#include <hip/hip_runtime.h>
#include <math.h>

// ---------------------------------------------------------------------------
// FeatureMatching: conv tower -> top-k keypoints -> softmax corr gather ->
// weighted DLT -> LAPACK-faithful sgesdd(QR path) SVD for H = Vh[:,:,-1].
// All f32. B=2, C=256, H=W=64, HW=4096, K=512.
// R1: register-blocked convs (16 oc/block), weights in LDS, IC_STEP staging.
// R2: fm_wts -> fm_qgather + fm_corr (tiled GEMM w/ online softmax partials)
//     + fm_comb (merge partials, gather numerator).
// ---------------------------------------------------------------------------

#define HW4 4096
#define NIMG 4   // imgs 0,1 = rgb batches; 2,3 = ir batches

// ws layout (floats)
#define OFF_X1   0L
#define OFF_X2   (OFF_X1 + 4L*128*4096)
#define OFF_RESP (OFF_X2 + 4L*128*4096)
#define OFF_INVN (OFF_RESP + 4L*4096)
#define OFF_TOPI (OFF_INVN + 4L*4096)      /* 4*512 ints */
#define OFF_WTS  (OFF_TOPI + 4L*512)
#define OFF_A    (OFF_WTS + 2L*512)
// qn + partials alias the x1 region (free after conv3):
//   qn:       [2][512][64]  = 65536 floats
//   partials: [2][512][16][2] = 32768 floats
#define OFF_QN   OFF_X1
#define OFF_PART (OFF_X1 + 65536L)

#define NSPLIT 16   // j-splits in fm_corr (each covers 256 cols)

__device__ __forceinline__ float silu_f(float y) { return y / (1.f + expf(-y)); }

// ---------------- conv1: 1x1 256->128 + BN + SiLU (16 oc per block) --------
__global__ __launch_bounds__(256) void fm_conv1(
    const float* __restrict__ rgb, const float* __restrict__ ir,
    const float* __restrict__ w, const float* __restrict__ g,
    const float* __restrict__ bb, const float* __restrict__ mm,
    const float* __restrict__ vv, float* __restrict__ x1) {
  __shared__ float wl[256*16];   // [ic][o]
  int bid = blockIdx.x;
  int pblk = bid & 15, ocg = (bid >> 4) & 7, img = bid >> 7;
  int oc0 = ocg * 16;
  int tid = threadIdx.x;
  const float* src = (img < 2) ? (rgb + (long)img*256*HW4) : (ir + (long)(img-2)*256*HW4);
  for (int i = tid; i < 4096; i += 256) {
    int o = i & 15, ic = i >> 4;
    wl[i] = w[(oc0 + o)*256 + ic];
  }
  __syncthreads();
  int p = pblk*256 + tid;
  float acc[16];
  #pragma unroll
  for (int o = 0; o < 16; ++o) acc[o] = 0.f;
  #pragma unroll 4
  for (int ic = 0; ic < 256; ++ic) {
    float v = src[ic*HW4 + p];
    #pragma unroll
    for (int o = 0; o < 16; ++o) acc[o] = fmaf(wl[ic*16 + o], v, acc[o]);
  }
  #pragma unroll
  for (int o = 0; o < 16; ++o) {
    int oc = oc0 + o;
    float inv = 1.f / sqrtf(vv[oc] + 1e-5f);
    float y = (acc[o] - mm[oc]) * (g[oc]*inv) + bb[oc];
    x1[((long)img*128 + oc)*HW4 + p] = silu_f(y);
  }
}

// ---------------- conv3: 3x3 128->128 SAME + BN+SiLU + BN_e+ReLU -----------
#define C3_ICS 4
__global__ __launch_bounds__(256) void fm_conv3(
    const float* __restrict__ x1, const float* __restrict__ w,
    const float* __restrict__ g1, const float* __restrict__ b1,
    const float* __restrict__ m1, const float* __restrict__ v1,
    const float* __restrict__ ge, const float* __restrict__ be,
    const float* __restrict__ me, const float* __restrict__ ve,
    float* __restrict__ x2) {
  __shared__ float t[C3_ICS][18*18];
  __shared__ float wv[C3_ICS][16*9];
  int bid = blockIdx.x;
  int tile = bid & 15, ocg = (bid >> 4) & 7, img = bid >> 7;
  int oc0 = ocg * 16;
  int ty0 = (tile >> 2) * 16, tx0 = (tile & 3) * 16;
  int tid = threadIdx.x;
  int ly = tid >> 4, lx = tid & 15;
  float acc[16];
  #pragma unroll
  for (int o = 0; o < 16; ++o) acc[o] = 0.f;
  const float* xim = x1 + (long)img*128*HW4;
  for (int ic0 = 0; ic0 < 128; ic0 += C3_ICS) {
    for (int i = tid; i < C3_ICS*324; i += 256) {
      int q = i / 324, r = i - q*324;
      int ry = r / 18, rx = r - ry*18;
      int gy = ty0 + ry - 1, gx = tx0 + rx - 1;
      float val = 0.f;
      if (gy >= 0 && gy < 64 && gx >= 0 && gx < 64)
        val = xim[(long)(ic0 + q)*HW4 + gy*64 + gx];
      t[q][r] = val;
    }
    for (int i = tid; i < C3_ICS*144; i += 256) {
      int q = i / 144, r = i - q*144;
      int o = r / 9, k = r - o*9;
      wv[q][r] = w[((long)(oc0 + o)*128 + ic0 + q)*9 + k];
    }
    __syncthreads();
    #pragma unroll
    for (int q = 0; q < C3_ICS; ++q) {
      float n0 = t[q][ly*18 + lx],     n1 = t[q][ly*18 + lx + 1],     n2 = t[q][ly*18 + lx + 2];
      float n3 = t[q][(ly+1)*18 + lx], n4 = t[q][(ly+1)*18 + lx + 1], n5 = t[q][(ly+1)*18 + lx + 2];
      float n6 = t[q][(ly+2)*18 + lx], n7 = t[q][(ly+2)*18 + lx + 1], n8 = t[q][(ly+2)*18 + lx + 2];
      #pragma unroll
      for (int o = 0; o < 16; ++o) {
        const float* wp = &wv[q][o*9];
        float a = acc[o];
        a = fmaf(wp[0], n0, a);
        a = fmaf(wp[1], n1, a);
        a = fmaf(wp[2], n2, a);
        a = fmaf(wp[3], n3, a);
        a = fmaf(wp[4], n4, a);
        a = fmaf(wp[5], n5, a);
        a = fmaf(wp[6], n6, a);
        a = fmaf(wp[7], n7, a);
        a = fmaf(wp[8], n8, a);
        acc[o] = a;
      }
    }
    __syncthreads();
  }
  int p = (ty0 + ly)*64 + tx0 + lx;
  #pragma unroll
  for (int o = 0; o < 16; ++o) {
    int oc = oc0 + o;
    float inv1 = 1.f / sqrtf(v1[oc] + 1e-5f);
    float y = (acc[o] - m1[oc]) * (g1[oc]*inv1) + b1[oc];
    y = silu_f(y);
    float inve = 1.f / sqrtf(ve[oc] + 1e-5f);
    float z = (y - me[oc]) * (ge[oc]*inve) + be[oc];
    z = fmaxf(z, 0.f);
    x2[((long)img*128 + oc)*HW4 + p] = z;
  }
}

// ---------------- conv2: 1x1 128->64 + BN + SiLU -> desc (into d_out) ------
__global__ __launch_bounds__(256) void fm_conv2(
    const float* __restrict__ x2, const float* __restrict__ w,
    const float* __restrict__ g, const float* __restrict__ bb,
    const float* __restrict__ mm, const float* __restrict__ vv,
    float* __restrict__ out) {
  __shared__ float wl[128*16];   // [ic][o]
  int bid = blockIdx.x;
  int pblk = bid & 15, ocg = (bid >> 4) & 3, img = bid >> 6;
  int oc0 = ocg * 16;
  int tid = threadIdx.x;
  for (int i = tid; i < 2048; i += 256) {
    int o = i & 15, ic = i >> 4;
    wl[i] = w[(oc0 + o)*128 + ic];
  }
  __syncthreads();
  int p = pblk*256 + tid;
  const float* src = x2 + (long)img*128*HW4;
  float acc[16];
  #pragma unroll
  for (int o = 0; o < 16; ++o) acc[o] = 0.f;
  #pragma unroll 4
  for (int ic = 0; ic < 128; ++ic) {
    float v = src[ic*HW4 + p];
    #pragma unroll
    for (int o = 0; o < 16; ++o) acc[o] = fmaf(wl[ic*16 + o], v, acc[o]);
  }
  #pragma unroll
  for (int o = 0; o < 16; ++o) {
    int oc = oc0 + o;
    float inv = 1.f / sqrtf(vv[oc] + 1e-5f);
    float y = (acc[o] - mm[oc]) * (g[oc]*inv) + bb[oc];
    out[18 + (long)img*262144 + oc*HW4 + p] = silu_f(y);
  }
}

// ---------------- resp + inv-norm ----------------
__global__ __launch_bounds__(256) void fm_resp(
    const float* __restrict__ out, float* __restrict__ resp, float* __restrict__ invn) {
  int t = blockIdx.x*256 + threadIdx.x;
  if (t >= NIMG*HW4) return;
  int img = t >> 12, p = t & 4095;
  const float* d = out + 18 + (long)img*262144;
  float s = 0.f;
  #pragma unroll
  for (int c = 0; c < 64; ++c) { float x = d[c*HW4 + p]; s = fmaf(x, x, s); }
  float r = sqrtf(s);
  resp[t] = r;
  invn[t] = 1.f / fmaxf(r, 1e-12f);
}

// ---------------- top-512 via full bitonic sort (desc value, asc index) ----
__global__ __launch_bounds__(1024) void fm_sort(
    const float* __restrict__ resp, int* __restrict__ topidx) {
  __shared__ unsigned long long keys[4096];
  int img = blockIdx.x, tid = threadIdx.x;
  const float* r = resp + (long)img*HW4;
  for (int i = tid; i < 4096; i += 1024) {
    unsigned int vb = __float_as_uint(r[i]);   // resp >= 0 -> bits monotone
    keys[i] = ((unsigned long long)vb << 32) | (unsigned int)(4095 - i);
  }
  __syncthreads();
  for (int k = 2; k <= 4096; k <<= 1) {
    for (int j = k >> 1; j > 0; j >>= 1) {
      for (int t = tid; t < 2048; t += 1024) {
        int i = 2*t - (t & (j - 1));
        int ixj = i ^ j;
        bool up = ((i & k) == 0);
        unsigned long long a = keys[i], b = keys[ixj];
        if ((a < b) == up) { keys[i] = b; keys[ixj] = a; }
      }
      __syncthreads();
    }
  }
  if (tid < 512) topidx[img*512 + tid] = 4095 - (int)(keys[tid] & 0xFFFFFFFFull);
}

// ---------------- qgather: qn[b][k][c] = d1[c][row]*in1[row] ---------------
__global__ __launch_bounds__(256) void fm_qgather(
    const float* __restrict__ out, const float* __restrict__ invn,
    const int* __restrict__ topidx, float* __restrict__ qn) {
  int tid = threadIdx.x;
  int kp = blockIdx.x*4 + (tid >> 6);     // 0..1023
  int c = tid & 63;
  int b = kp >> 9, k = kp & 511;
  int row = topidx[b*512 + k];
  const float* d1 = out + 18 + (long)b*262144;
  qn[(long)kp*64 + c] = d1[c*HW4 + row] * invn[(long)b*HW4 + row];
}

// ---------------- corr: tiled GEMM + online softmax partials ---------------
// block: 256 thr = 8 row-groups (ty) x 32 col-lanes (tx).
// Each block: 32 keypoints x 256 columns (2 tiles of 128), c = 64.
__global__ __launch_bounds__(256) void fm_corr(
    const float* __restrict__ out, const float* __restrict__ invn,
    const float* __restrict__ qn, float* __restrict__ part) {
  __shared__ float Qs[32*64];        // [row][c]
  __shared__ float Ds[64*128];       // [c][col]
  int tid = threadIdx.x;
  int tx = tid & 31, ty = tid >> 5;
  int jsplit = blockIdx.x;           // 0..15
  int kg = blockIdx.y;               // 0..15
  int b = blockIdx.z;                // 0..1
  int k0 = kg*32;
  const float* d2 = out + 18 + (long)(2 + b)*262144;
  const float* in2 = invn + (long)(2 + b)*HW4;
  // stage Q tile: 2048 floats
  {
    const float4* src = (const float4*)(qn + ((long)b*512 + k0)*64);
    float4* dst = (float4*)Qs;
    dst[tid] = src[tid];
    dst[tid + 256] = src[tid + 256];
  }
  float m[4], s[4];
  #pragma unroll
  for (int r = 0; r < 4; ++r) { m[r] = -INFINITY; s[r] = 0.f; }
  #pragma unroll
  for (int tile = 0; tile < 2; ++tile) {
    int j0 = jsplit*256 + tile*128;
    __syncthreads();   // protect Ds from previous tile's readers
    // stage D tile [64][128]: 2048 float4s, 8 per thread
    {
      float4* dst = (float4*)Ds;
      #pragma unroll
      for (int t = 0; t < 8; ++t) {
        int i = tid + 256*t;
        int c = i >> 5, col4 = i & 31;
        dst[i] = *(const float4*)(d2 + (long)c*HW4 + j0 + col4*4);
      }
    }
    __syncthreads();
    float acc[4][4];
    #pragma unroll
    for (int r = 0; r < 4; ++r)
      #pragma unroll
      for (int cc = 0; cc < 4; ++cc) acc[r][cc] = 0.f;
    const float4* Ds4 = (const float4*)Ds;
    #pragma unroll 4
    for (int c = 0; c < 64; ++c) {
      float4 dv = Ds4[c*32 + tx];
      #pragma unroll
      for (int r = 0; r < 4; ++r) {
        float qv = Qs[(ty*4 + r)*64 + c];
        acc[r][0] = fmaf(qv, dv.x, acc[r][0]);
        acc[r][1] = fmaf(qv, dv.y, acc[r][1]);
        acc[r][2] = fmaf(qv, dv.z, acc[r][2]);
        acc[r][3] = fmaf(qv, dv.w, acc[r][3]);
      }
    }
    // epilogue: scale by in2[j], online (m,s) per row
    float i0 = in2[j0 + tx*4 + 0];
    float i1 = in2[j0 + tx*4 + 1];
    float i2 = in2[j0 + tx*4 + 2];
    float i3 = in2[j0 + tx*4 + 3];
    #pragma unroll
    for (int r = 0; r < 4; ++r) {
      float v0 = acc[r][0]*i0, v1 = acc[r][1]*i1, v2 = acc[r][2]*i2, v3 = acc[r][3]*i3;
      float vm = fmaxf(fmaxf(v0, v1), fmaxf(v2, v3));
      float nm = fmaxf(m[r], vm);
      s[r] = s[r]*expf(m[r] - nm) + expf(v0 - nm) + expf(v1 - nm) + expf(v2 - nm) + expf(v3 - nm);
      m[r] = nm;
    }
  }
  // reduce (m,s) across the 32 tx lanes (within each 32-lane half-wave)
  #pragma unroll
  for (int off = 1; off < 32; off <<= 1) {
    #pragma unroll
    for (int r = 0; r < 4; ++r) {
      float om = __shfl_xor(m[r], off);
      float os = __shfl_xor(s[r], off);
      float nm = fmaxf(m[r], om);
      s[r] = s[r]*expf(m[r] - nm) + os*expf(om - nm);
      m[r] = nm;
    }
  }
  if (tx == 0) {
    #pragma unroll
    for (int r = 0; r < 4; ++r) {
      long idx = (((long)b*512 + k0 + ty*4 + r)*NSPLIT + jsplit)*2;
      part[idx] = m[r];
      part[idx + 1] = s[r];
    }
  }
}

// ---------------- comb: merge partials + numerator -> wts ------------------
__global__ __launch_bounds__(256) void fm_comb(
    const float* __restrict__ out, const float* __restrict__ invn,
    const int* __restrict__ topidx, const float* __restrict__ qn,
    const float* __restrict__ part, float* __restrict__ wts) {
  int tid = threadIdx.x;
  int kp = blockIdx.x*4 + (tid >> 6);     // 0..1023
  int lane = tid & 63;
  int b = kp >> 9, k = kp & 511;
  int col = topidx[(2 + b)*512 + k];
  const float* d2 = out + 18 + (long)(2 + b)*262144;
  float dot = qn[(long)kp*64 + lane] * d2[lane*HW4 + col];
  #pragma unroll
  for (int off = 1; off < 64; off <<= 1) dot += __shfl_xor(dot, off);
  if (lane == 0) {
    const float* pp = part + (long)kp*NSPLIT*2;
    float M = -INFINITY;
    #pragma unroll
    for (int i = 0; i < NSPLIT; ++i) M = fmaxf(M, pp[2*i]);
    float S = 0.f;
    #pragma unroll
    for (int i = 0; i < NSPLIT; ++i) S += pp[2*i + 1]*expf(pp[2*i] - M);
    float v = dot * invn[(long)(2 + b)*HW4 + col];
    wts[b*512 + k] = expf(v - M)/S;
  }
}

// ---------------- build DLT rows ----------------
__global__ __launch_bounds__(256) void fm_build(
    const int* __restrict__ topidx, const float* __restrict__ wts,
    float* __restrict__ A) {
  int t = blockIdx.x*256 + threadIdx.x;
  if (t >= 1024) return;
  int b = t >> 9, k = t & 511;
  int i1 = topidx[b*512 + k], i2 = topidx[(2 + b)*512 + k];
  float w = wts[b*512 + k];
  float x1 = (float)(i1 & 63) / 63.f * 2.f - 1.f;
  float y1 = (float)(i1 >> 6) / 63.f * 2.f - 1.f;
  float x2 = (float)(i2 & 63) / 63.f * 2.f - 1.f;
  float y2 = (float)(i2 >> 6) / 63.f * 2.f - 1.f;
  float* r = A + ((long)b*1024 + 2*k)*9;
  r[0] = x1*w;  r[1] = y1*w;  r[2] = w;
  r[3] = 0.f;   r[4] = 0.f;   r[5] = 0.f;
  r[6] = (-x2*x1)*w; r[7] = (-x2*y1)*w; r[8] = (-x2)*w;
  r[9]  = 0.f;  r[10] = 0.f;  r[11] = 0.f;
  r[12] = x1*w; r[13] = y1*w; r[14] = w;
  r[15] = (-y2*x1)*w; r[16] = (-y2*y1)*w; r[17] = (-y2)*w;
}

// =========================== LAPACK ports ===================================
// slartg, LAPACK >= 3.10 convention: c >= 0, r = sign(f)*hypot.
__device__ void lap_slartg(float f, float g, float* cs, float* sn, float* r) {
  if (g == 0.f) { *cs = 1.f; *sn = 0.f; *r = f; }
  else if (f == 0.f) { *cs = 0.f; *sn = copysignf(1.f, g); *r = fabsf(g); }
  else {
    float d = sqrtf(f*f + g*g);
    *cs = fabsf(f) / d;
    *r = copysignf(d, f);
    *sn = g / (*r);
  }
}

__device__ void lap_slas2(float f, float g, float h, float* ssmin, float* ssmax) {
  float fa = fabsf(f), ga = fabsf(g), ha = fabsf(h);
  float fhmn = fminf(fa, ha), fhmx = fmaxf(fa, ha);
  if (fhmn == 0.f) {
    *ssmin = 0.f;
    if (fhmx == 0.f) *ssmax = ga;
    else {
      float mx = fmaxf(fhmx, ga), mn = fminf(fhmx, ga);
      float q = mn / mx;
      *ssmax = mx * sqrtf(1.f + q*q);
    }
  } else {
    if (ga < fhmx) {
      float as_ = 1.f + fhmn/fhmx;
      float at_ = (fhmx - fhmn)/fhmx;
      float au = ga/fhmx; au = au*au;
      float c = 2.f / (sqrtf(as_*as_ + au) + sqrtf(at_*at_ + au));
      *ssmin = fhmn*c;
      *ssmax = fhmx/c;
    } else {
      float au = fhmx/ga;
      if (au == 0.f) { *ssmin = (fhmn*fhmx)/ga; *ssmax = ga; }
      else {
        float as_ = 1.f + fhmn/fhmx;
        float at_ = (fhmx - fhmn)/fhmx;
        float t1 = as_*au, t2 = at_*au;
        float c = 1.f / (sqrtf(1.f + t1*t1) + sqrtf(1.f + t2*t2));
        float smn = (fhmn*c)*au;
        *ssmin = smn + smn;
        *ssmax = ga/(c + c);
      }
    }
  }
}

__device__ void lap_slasv2(float f, float g, float h, float* ssmin, float* ssmax,
                           float* snr, float* csr, float* snl, float* csl) {
  const float epsv = 5.9604645e-08f;
  float ft = f, fa = fabsf(f), ht = h, ha = fabsf(h);
  int pmax = 1;
  bool swap_ = (ha > fa);
  if (swap_) { pmax = 3; float tmp = ft; ft = ht; ht = tmp; tmp = fa; fa = ha; ha = tmp; }
  float gt = g, ga = fabsf(gt);
  float clt = 0.f, crt = 0.f, slt = 0.f, srt = 0.f;
  if (ga == 0.f) { *ssmin = ha; *ssmax = fa; clt = 1.f; crt = 1.f; slt = 0.f; srt = 0.f; }
  else {
    bool gasmal = true;
    if (ga > fa) {
      pmax = 2;
      if ((fa/ga) < epsv) {
        gasmal = false;
        *ssmax = ga;
        if (ha > 1.f) *ssmin = fa/(ga/ha); else *ssmin = (fa/ga)*ha;
        clt = 1.f; slt = ht/gt; srt = 1.f; crt = ft/gt;
      }
    }
    if (gasmal) {
      float d = fa - ha, l;
      if (d == fa) l = 1.f; else l = d/fa;
      float m_ = gt/ft;
      float t = 2.f - l;
      float mm2 = m_*m_, tt = t*t;
      float s = sqrtf(tt + mm2);
      float r_ = (l == 0.f) ? fabsf(m_) : sqrtf(l*l + mm2);
      float a = 0.5f*(s + r_);
      *ssmin = ha/a;
      *ssmax = fa*a;
      if (mm2 == 0.f) {
        if (l == 0.f) t = copysignf(2.f, ft)*copysignf(1.f, gt);
        else t = gt/copysignf(d, ft) + m_/t;
      } else {
        t = (m_/(s + t) + m_/(r_ + l))*(1.f + a);
      }
      float l2 = sqrtf(t*t + 4.f);
      crt = 2.f/l2;
      srt = t/l2;
      clt = (crt + srt*m_)/a;
      slt = (ht/ft)*srt/a;
    }
  }
  if (swap_) { *csl = srt; *snl = crt; *csr = slt; *snr = clt; }
  else { *csl = clt; *snl = slt; *csr = crt; *snr = srt; }
  float tsign = 1.f;
  if (pmax == 1) tsign = copysignf(1.f, *csr)*copysignf(1.f, *csl)*copysignf(1.f, f);
  if (pmax == 2) tsign = copysignf(1.f, *snr)*copysignf(1.f, *csl)*copysignf(1.f, g);
  if (pmax == 3) tsign = copysignf(1.f, *snr)*copysignf(1.f, *snl)*copysignf(1.f, h);
  *ssmax = copysignf(*ssmax, tsign);
  *ssmin = copysignf(*ssmin, tsign*copysignf(1.f, f)*copysignf(1.f, h));
}

// sbdsqr for n=9 upper bidiagonal, NCVT=9 (VT rotated), NRU=NCC=0, TOL>0.
__device__ void lap_bdsqr9(float* dd, float* ee, float VT[][9]) {
  const float eps_ = 5.9604645e-08f;
  const float unfl_ = 1.17549435e-38f;
  const float tol_ = 10.f*eps_;
  const int n = 9;
  for (int i = 0; i < 9; ++i) for (int j = 0; j < 9; ++j) VT[i][j] = (i == j) ? 1.f : 0.f;
  float sminoa = fabsf(dd[0]);
  if (sminoa != 0.f) {
    float mu = sminoa;
    for (int i = 1; i < n; ++i) {
      mu = fabsf(dd[i])*(mu/(mu + fabsf(ee[i-1])));
      sminoa = fminf(sminoa, mu);
      if (sminoa == 0.f) break;
    }
  }
  sminoa = sminoa / 3.f;
  float thresh = fmaxf(tol_*sminoa, 486.f*unfl_);
  int m = n, iter = 0, oldll = -1, oldm = -1, idir = 0;
  float sminl = 0.f;
  float rc[8], rs[8];
  int guard = 0;
  while (guard++ < 20000) {
    if (m <= 1) break;
    if (iter > 486) break;
    float smax = fabsf(dd[m-1]);
    int ll = 0; bool split = false;
    for (int lll = 1; lll <= m - 1; ++lll) {
      int l2 = m - lll;
      float abss = fabsf(dd[l2-1]);
      float abse = fabsf(ee[l2-1]);
      if (abse <= thresh) { ll = l2; split = true; break; }
      smax = fmaxf(smax, fmaxf(abss, abse));
    }
    if (split) {
      ee[ll-1] = 0.f;
      if (ll == m - 1) { m = m - 1; continue; }
    } else ll = 0;
    ll = ll + 1;
    if (ll == m - 1) {
      float sigmn, sigmx, sinr, cosr, sinl_, cosl_;
      lap_slasv2(dd[m-2], ee[m-2], dd[m-1], &sigmn, &sigmx, &sinr, &cosr, &sinl_, &cosl_);
      dd[m-2] = sigmx; ee[m-2] = 0.f; dd[m-1] = sigmn;
      for (int j = 0; j < 9; ++j) {
        float xt = VT[m-2][j], yt = VT[m-1][j];
        VT[m-2][j] = cosr*xt + sinr*yt;
        VT[m-1][j] = cosr*yt - sinr*xt;
      }
      m -= 2; continue;
    }
    if (ll > oldm || m < oldll) idir = (fabsf(dd[ll-1]) >= fabsf(dd[m-1])) ? 1 : 2;
    bool conv = false;
    if (idir == 1) {
      if (fabsf(ee[m-2]) <= tol_*fabsf(dd[m-1])) { ee[m-2] = 0.f; continue; }
      float mu = fabsf(dd[ll-1]);
      sminl = mu;
      for (int lll = ll; lll <= m - 1; ++lll) {
        if (fabsf(ee[lll-1]) <= tol_*mu) { ee[lll-1] = 0.f; conv = true; break; }
        mu = fabsf(dd[lll])*(mu/(mu + fabsf(ee[lll-1])));
        sminl = fminf(sminl, mu);
      }
    } else {
      if (fabsf(ee[ll-1]) <= tol_*fabsf(dd[ll-1])) { ee[ll-1] = 0.f; continue; }
      float mu = fabsf(dd[m-1]);
      sminl = mu;
      for (int lll = m - 1; lll >= ll; --lll) {
        if (fabsf(ee[lll-1]) <= tol_*mu) { ee[lll-1] = 0.f; conv = true; break; }
        mu = fabsf(dd[lll-1])*(mu/(mu + fabsf(ee[lll-1])));
        sminl = fminf(sminl, mu);
      }
    }
    if (conv) continue;
    oldll = ll; oldm = m;
    float shift = 0.f, rdum;
    if (!((float)n*tol_*(sminl/smax) <= fmaxf(eps_, 0.01f*tol_))) {
      float sll;
      if (idir == 1) { sll = fabsf(dd[ll-1]); lap_slas2(dd[m-2], ee[m-2], dd[m-1], &shift, &rdum); }
      else           { sll = fabsf(dd[m-1]);  lap_slas2(dd[ll-1], ee[ll-1], dd[ll], &shift, &rdum); }
      if (sll > 0.f) { float q = shift/sll; if (q*q < eps_) shift = 0.f; }
    }
    iter += m - ll;
    if (shift == 0.f) {
      if (idir == 1) {
        float cs = 1.f, oldcs = 1.f, sn = 0.f, oldsn = 0.f, r;
        for (int i = ll; i <= m - 1; ++i) {
          lap_slartg(dd[i-1]*cs, ee[i-1], &cs, &sn, &r);
          if (i > ll) ee[i-2] = oldsn*r;
          float dn;
          lap_slartg(oldcs*r, dd[i]*sn, &oldcs, &oldsn, &dn);
          dd[i-1] = dn;
          rc[i-ll] = cs; rs[i-ll] = sn;
        }
        float h2 = dd[m-1]*cs;
        dd[m-1] = h2*oldcs;
        ee[m-2] = h2*oldsn;
        for (int k2 = 0; k2 <= m - ll - 1; ++k2) {
          int r0 = ll + k2 - 1;
          float c = rc[k2], s = rs[k2];
          for (int j = 0; j < 9; ++j) {
            float t = VT[r0+1][j];
            VT[r0+1][j] = c*t - s*VT[r0][j];
            VT[r0][j]   = s*t + c*VT[r0][j];
          }
        }
        if (fabsf(ee[m-2]) <= thresh) ee[m-2] = 0.f;
      } else {
        float cs = 1.f, oldcs = 1.f, sn = 0.f, oldsn = 0.f, r;
        for (int i = m; i >= ll + 1; --i) {
          lap_slartg(dd[i-1]*cs, ee[i-2], &cs, &sn, &r);
          if (i < m) ee[i-1] = oldsn*r;
          float dn;
          lap_slartg(oldcs*r, dd[i-2]*sn, &oldcs, &oldsn, &dn);
          dd[i-1] = dn;
          rc[i-ll-1] = oldcs; rs[i-ll-1] = -oldsn;
        }
        float h2 = dd[ll-1]*cs;
        dd[ll-1] = h2*oldcs;
        ee[ll-1] = h2*oldsn;
        for (int k2 = m - ll - 1; k2 >= 0; --k2) {
          int r0 = ll + k2 - 1;
          float c = rc[k2], s = rs[k2];
          for (int j = 0; j < 9; ++j) {
            float t = VT[r0+1][j];
            VT[r0+1][j] = c*t - s*VT[r0][j];
            VT[r0][j]   = s*t + c*VT[r0][j];
          }
        }
        if (fabsf(ee[ll-1]) <= thresh) ee[ll-1] = 0.f;
      }
    } else {
      if (idir == 1) {
        float f2 = (fabsf(dd[ll-1]) - shift)*(copysignf(1.f, dd[ll-1]) + shift/dd[ll-1]);
        float g2 = ee[ll-1];
        for (int i = ll; i <= m - 1; ++i) {
          float cr, sr, cl, sl, r;
          lap_slartg(f2, g2, &cr, &sr, &r);
          if (i > ll) ee[i-2] = r;
          f2 = cr*dd[i-1] + sr*ee[i-1];
          ee[i-1] = cr*ee[i-1] - sr*dd[i-1];
          g2 = sr*dd[i];
          dd[i] = cr*dd[i];
          lap_slartg(f2, g2, &cl, &sl, &r);
          dd[i-1] = r;
          f2 = cl*ee[i-1] + sl*dd[i];
          dd[i] = cl*dd[i] - sl*ee[i-1];
          if (i < m - 1) { g2 = sl*ee[i]; ee[i] = cl*ee[i]; }
          rc[i-ll] = cr; rs[i-ll] = sr;
        }
        ee[m-2] = f2;
        for (int k2 = 0; k2 <= m - ll - 1; ++k2) {
          int r0 = ll + k2 - 1;
          float c = rc[k2], s = rs[k2];
          for (int j = 0; j < 9; ++j) {
            float t = VT[r0+1][j];
            VT[r0+1][j] = c*t - s*VT[r0][j];
            VT[r0][j]   = s*t + c*VT[r0][j];
          }
        }
        if (fabsf(ee[m-2]) <= thresh) ee[m-2] = 0.f;
      } else {
        float f2 = (fabsf(dd[m-1]) - shift)*(copysignf(1.f, dd[m-1]) + shift/dd[m-1]);
        float g2 = ee[m-2];
        for (int i = m; i >= ll + 1; --i) {
          float cr, sr, cl, sl, r;
          lap_slartg(f2, g2, &cr, &sr, &r);
          if (i < m) ee[i-1] = r;
          f2 = cr*dd[i-1] + sr*ee[i-2];
          ee[i-2] = cr*ee[i-2] - sr*dd[i-1];
          g2 = sr*dd[i-2];
          dd[i-2] = cr*dd[i-2];
          lap_slartg(f2, g2, &cl, &sl, &r);
          dd[i-1] = r;
          f2 = cl*ee[i-2] + sl*dd[i-2];
          dd[i-2] = cl*dd[i-2] - sl*ee[i-2];
          if (i > ll + 1) { g2 = sl*ee[i-3]; ee[i-3] = cl*ee[i-3]; }
          rc[i-ll-1] = cl; rs[i-ll-1] = -sl;
        }
        ee[ll-1] = f2;
        if (fabsf(ee[ll-1]) <= thresh) ee[ll-1] = 0.f;
        for (int k2 = m - ll - 1; k2 >= 0; --k2) {
          int r0 = ll + k2 - 1;
          float c = rc[k2], s = rs[k2];
          for (int j = 0; j < 9; ++j) {
            float t = VT[r0+1][j];
            VT[r0+1][j] = c*t - s*VT[r0][j];
            VT[r0][j]   = s*t + c*VT[r0][j];
          }
        }
      }
    }
  }
  for (int i = 0; i < n; ++i) {
    if (dd[i] < 0.f) {
      dd[i] = -dd[i];
      for (int j = 0; j < 9; ++j) VT[i][j] = -VT[i][j];
    }
  }
  for (int i = 1; i <= n - 1; ++i) {
    int isub = 1; float smin2 = dd[0];
    for (int j = 2; j <= n + 1 - i; ++j)
      if (dd[j-1] <= smin2) { isub = j; smin2 = dd[j-1]; }
    int tgt = n + 1 - i;
    if (isub != tgt) {
      dd[isub-1] = dd[tgt-1]; dd[tgt-1] = smin2;
      for (int j = 0; j < 9; ++j) {
        float t = VT[isub-1][j]; VT[isub-1][j] = VT[tgt-1][j]; VT[tgt-1][j] = t;
      }
    }
  }
}

// ---------------- SVD kernel: QR(1024x9) block-parallel, rest thread-0 -----
__global__ __launch_bounds__(256) void fm_svd(
    const float* __restrict__ Aglob, float* __restrict__ outH) {
  __shared__ float As[1024*9];
  __shared__ float red[256];
  __shared__ float bc[4];
  __shared__ float Rm[9][9], VT[9][9], PT[9][9];
  __shared__ float dd[9], ee[9], taup[9];
  int b = blockIdx.x, tid = threadIdx.x;
  const float* Ab = Aglob + (long)b*1024*9;
  for (int i = tid; i < 9216; i += 256) As[i] = Ab[i];
  __syncthreads();
  for (int k = 0; k < 9; ++k) {
    float ps = 0.f;
    for (int r = k + 1 + tid; r < 1024; r += 256) { float x = As[r*9 + k]; ps = fmaf(x, x, ps); }
    red[tid] = ps; __syncthreads();
    for (int off = 128; off > 0; off >>= 1) {
      if (tid < off) red[tid] += red[tid + off];
      __syncthreads();
    }
    if (tid == 0) {
      float ssq = red[0];
      float alpha = As[k*9 + k];
      float tau = 0.f, sc = 0.f, beta = alpha;
      if (ssq != 0.f) {
        beta = -copysignf(sqrtf(alpha*alpha + ssq), alpha);
        tau = (beta - alpha)/beta;
        sc = 1.f/(alpha - beta);
      }
      bc[0] = tau; bc[1] = sc; bc[2] = beta;
    }
    __syncthreads();
    float tau = bc[0], sc = bc[1];
    if (tau != 0.f) {
      for (int r = k + 1 + tid; r < 1024; r += 256) As[r*9 + k] *= sc;
    }
    __syncthreads();
    if (tau != 0.f) {
      for (int j = k + 1; j < 9; ++j) {
        float pd = 0.f;
        for (int r = k + 1 + tid; r < 1024; r += 256) pd = fmaf(As[r*9 + k], As[r*9 + j], pd);
        red[tid] = pd; __syncthreads();
        for (int off = 128; off > 0; off >>= 1) {
          if (tid < off) red[tid] += red[tid + off];
          __syncthreads();
        }
        float s = (red[0] + As[k*9 + j]) * tau;
        if (tid == 0) As[k*9 + j] -= s;
        for (int r = k + 1 + tid; r < 1024; r += 256) As[r*9 + j] -= s*As[r*9 + k];
        __syncthreads();
      }
    }
    if (tid == 0) As[k*9 + k] = bc[2];
    __syncthreads();
  }
  if (tid == 0) {
    for (int i = 0; i < 9; ++i)
      for (int j = 0; j < 9; ++j)
        Rm[i][j] = (j >= i) ? As[i*9 + j] : 0.f;
    for (int i = 0; i < 9; ++i) {
      float alpha = Rm[i][i];
      float ssq = 0.f;
      for (int r = i + 1; r < 9; ++r) ssq += Rm[r][i]*Rm[r][i];
      float tauq = 0.f, beta = alpha;
      if (ssq != 0.f) {
        beta = -copysignf(sqrtf(alpha*alpha + ssq), alpha);
        tauq = (beta - alpha)/beta;
        float sc = 1.f/(alpha - beta);
        for (int r = i + 1; r < 9; ++r) Rm[r][i] *= sc;
      }
      dd[i] = beta;
      if (tauq != 0.f) {
        for (int j = i + 1; j < 9; ++j) {
          float s = Rm[i][j];
          for (int r = i + 1; r < 9; ++r) s += Rm[r][i]*Rm[r][j];
          s *= tauq;
          Rm[i][j] -= s;
          for (int r = i + 1; r < 9; ++r) Rm[r][j] -= s*Rm[r][i];
        }
      }
      if (i < 8) {
        float alpha2 = Rm[i][i+1];
        float ssq2 = 0.f;
        for (int c = i + 2; c < 9; ++c) ssq2 += Rm[i][c]*Rm[i][c];
        float tp = 0.f, beta2 = alpha2;
        if (ssq2 != 0.f) {
          beta2 = -copysignf(sqrtf(alpha2*alpha2 + ssq2), alpha2);
          tp = (beta2 - alpha2)/beta2;
          float sc = 1.f/(alpha2 - beta2);
          for (int c = i + 2; c < 9; ++c) Rm[i][c] *= sc;
        }
        ee[i] = beta2;
        taup[i] = tp;
        if (tp != 0.f) {
          for (int r = i + 1; r < 9; ++r) {
            float s = Rm[r][i+1];
            for (int c = i + 2; c < 9; ++c) s += Rm[i][c]*Rm[r][c];
            s *= tp;
            Rm[r][i+1] -= s;
            for (int c = i + 2; c < 9; ++c) Rm[r][c] -= s*Rm[i][c];
          }
        }
      }
    }
    for (int i = 0; i < 9; ++i) for (int j = 0; j < 9; ++j) PT[i][j] = (i == j) ? 1.f : 0.f;
    for (int i = 0; i < 8; ++i) {
      float tp = taup[i];
      if (tp == 0.f) continue;
      for (int j = 0; j < 9; ++j) {
        float s = PT[i+1][j];
        for (int r = i + 2; r < 9; ++r) s += Rm[i][r]*PT[r][j];
        s *= tp;
        PT[i+1][j] -= s;
        for (int r = i + 2; r < 9; ++r) PT[r][j] -= s*Rm[i][r];
      }
    }
    lap_bdsqr9(dd, ee, VT);
    for (int i = 0; i < 9; ++i) {
      float s = 0.f;
      for (int k2 = 0; k2 < 9; ++k2) s += VT[i][k2]*PT[k2][8];
      outH[b*9 + i] = s;
    }
  }
}

// ===========================================================================
extern "C" void kernel_launch(void* const* d_in, const int* in_sizes, int n_in,
                              void* d_out, int out_size, void* d_ws, size_t ws_size,
                              hipStream_t stream) {
  const float* rgb  = (const float*)d_in[0];
  const float* ir   = (const float*)d_in[1];
  const float* w_dr = (const float*)d_in[2];
  const float* g_dr = (const float*)d_in[3];
  const float* b_dr = (const float*)d_in[4];
  const float* m_dr = (const float*)d_in[5];
  const float* v_dr = (const float*)d_in[6];
  const float* w_d1 = (const float*)d_in[7];
  const float* g_d1 = (const float*)d_in[8];
  const float* b_d1 = (const float*)d_in[9];
  const float* m_d1 = (const float*)d_in[10];
  const float* v_d1 = (const float*)d_in[11];
  const float* g_e  = (const float*)d_in[12];
  const float* b_e  = (const float*)d_in[13];
  const float* m_e  = (const float*)d_in[14];
  const float* v_e  = (const float*)d_in[15];
  const float* w_d2 = (const float*)d_in[16];
  const float* g_d2 = (const float*)d_in[17];
  const float* b_d2 = (const float*)d_in[18];
  const float* m_d2 = (const float*)d_in[19];
  const float* v_d2 = (const float*)d_in[20];

  float* out = (float*)d_out;
  float* ws  = (float*)d_ws;
  float* x1   = ws + OFF_X1;
  float* x2   = ws + OFF_X2;
  float* resp = ws + OFF_RESP;
  float* invn = ws + OFF_INVN;
  int*   topi = (int*)(ws + OFF_TOPI);
  float* wts  = ws + OFF_WTS;
  float* Amat = ws + OFF_A;
  float* qn   = ws + OFF_QN;     // aliases x1 (free after conv3)
  float* part = ws + OFF_PART;   // aliases x1

  fm_conv1<<<NIMG*8*16, 256, 0, stream>>>(rgb, ir, w_dr, g_dr, b_dr, m_dr, v_dr, x1);
  fm_conv3<<<NIMG*8*16, 256, 0, stream>>>(x1, w_d1, g_d1, b_d1, m_d1, v_d1,
                                          g_e, b_e, m_e, v_e, x2);
  fm_conv2<<<NIMG*4*16, 256, 0, stream>>>(x2, w_d2, g_d2, b_d2, m_d2, v_d2, out);
  fm_resp<<<(NIMG*HW4 + 255)/256, 256, 0, stream>>>(out, resp, invn);
  fm_sort<<<NIMG, 1024, 0, stream>>>(resp, topi);
  fm_qgather<<<256, 256, 0, stream>>>(out, invn, topi, qn);
  fm_corr<<<dim3(NSPLIT, 16, 2), 256, 0, stream>>>(out, invn, qn, part);
  fm_comb<<<256, 256, 0, stream>>>(out, invn, topi, qn, part, wts);
  fm_build<<<4, 256, 0, stream>>>(topi, wts, Amat);
  fm_svd<<<2, 256, 0, stream>>>(Amat, out);
}